// Round 5
// baseline (3651.797 us; speedup 1.0000x reference)
//
#include <hip/hip_runtime.h>
#include <cmath>

#define SEQ 2048
#define NB 64
#define VOC 128
#define DM 2176
#define NEG_INF -1e30f

typedef __attribute__((ext_vector_type(8))) short short8;
typedef __attribute__((ext_vector_type(4))) float f32x4;
typedef __attribute__((ext_vector_type(4))) unsigned int uint4v;
typedef __attribute__((ext_vector_type(2))) unsigned int uint2v;

// ---------- bf16 split helpers (hi = truncation, lo = remainder) ----------
__device__ __forceinline__ void splitf(float x, unsigned short& h, unsigned short& l) {
    unsigned int u = __float_as_uint(x);
    h = (unsigned short)(u >> 16);
    float d = x - __uint_as_float(u & 0xFFFF0000u);
    l = (unsigned short)(__float_as_uint(d) >> 16);
}
__device__ __forceinline__ unsigned int bfpair(float x0, float x1, unsigned int& lopair) {
    unsigned int u0 = __float_as_uint(x0), u1 = __float_as_uint(x1);
    float d0 = x0 - __uint_as_float(u0 & 0xFFFF0000u);
    float d1 = x1 - __uint_as_float(u1 & 0xFFFF0000u);
    lopair = (__float_as_uint(d0) >> 16) | (__float_as_uint(d1) & 0xFFFF0000u);
    return (u0 >> 16) | (u1 & 0xFFFF0000u);
}

// ------------------------------------------------------------------
// Naive tiled f32 GEMM (tiny GEMMs only). C[M,N] = A[M,K] @ B[K,N].
// ------------------------------------------------------------------
template<int TB>
__global__ __launch_bounds__(256) void gemm_f32(
    const float* __restrict__ A, int lda,
    const float* __restrict__ B, int ldb,
    float* __restrict__ C, int ldc,
    int M, int N, int K)
{
    __shared__ float As[16][64];
    __shared__ float Bs[16][65];
    const int bm = blockIdx.y * 64;
    const int bn = blockIdx.x * 64;
    const int t  = threadIdx.x;
    const int tx = t & 15, ty = t >> 4;
    float acc[4][4] = {};
    for (int k0 = 0; k0 < K; k0 += 16) {
        #pragma unroll
        for (int i = 0; i < 4; ++i) {
            int m = (t >> 4) + 16 * i;
            int k = t & 15;
            As[k][m] = A[(size_t)(bm + m) * lda + k0 + k];
        }
        if (TB == 0) {
            #pragma unroll
            for (int i = 0; i < 4; ++i) {
                int n = t & 63;
                int k = (t >> 6) + 4 * i;
                Bs[k][n] = B[(size_t)(k0 + k) * ldb + bn + n];
            }
        } else {
            #pragma unroll
            for (int i = 0; i < 4; ++i) {
                int k = t & 15;
                int n = (t >> 4) + 16 * i;
                Bs[k][n] = B[(size_t)(bn + n) * ldb + k0 + k];
            }
        }
        __syncthreads();
        #pragma unroll
        for (int kk = 0; kk < 16; ++kk) {
            float a[4], bb[4];
            #pragma unroll
            for (int i = 0; i < 4; ++i) a[i] = As[kk][ty * 4 + i];
            #pragma unroll
            for (int j = 0; j < 4; ++j) bb[j] = Bs[kk][tx * 4 + j];
            #pragma unroll
            for (int i = 0; i < 4; ++i)
                #pragma unroll
                for (int j = 0; j < 4; ++j)
                    acc[i][j] += a[i] * bb[j];
        }
        __syncthreads();
    }
    #pragma unroll
    for (int i = 0; i < 4; ++i) {
        size_t m = bm + ty * 4 + i;
        #pragma unroll
        for (int j = 0; j < 4; ++j)
            C[m * ldc + bn + tx * 4 + j] = acc[i][j];
    }
}

// ------------------------------------------------------------------
__global__ __launch_bounds__(256) void split_plain(
    const float* __restrict__ in, unsigned short* __restrict__ oh,
    unsigned short* __restrict__ ol, int n4)
{
    int i = blockIdx.x * 256 + threadIdx.x;
    if (i >= n4) return;
    f32x4 v = *(const f32x4*)(in + (size_t)i * 4);
    unsigned int h01, h23, l01, l23;
    h01 = bfpair(v[0], v[1], l01);
    h23 = bfpair(v[2], v[3], l23);
    *(uint2v*)(oh + (size_t)i * 4) = (uint2v){h01, h23};
    *(uint2v*)(ol + (size_t)i * 4) = (uint2v){l01, l23};
}

// ------------------------------------------------------------------
// Split + transpose: out[c][r] = in[(row0+r)*ld + c], r<NR, c<NC. out ld = NR.
// Grid (NR/32, NC/32), 256 threads.
// ------------------------------------------------------------------
__global__ __launch_bounds__(256) void splitT(
    const float* __restrict__ in, int ld, int row0,
    int NR, int NC,
    unsigned short* __restrict__ oh, unsigned short* __restrict__ ol)
{
    __shared__ float tile[32][33];
    const int r0 = blockIdx.x * 32, c0 = blockIdx.y * 32;
    const int t = threadIdx.x;
    const int x = t & 31, y = t >> 5;
    #pragma unroll
    for (int i = 0; i < 4; ++i) {
        int r = y + i * 8;
        tile[r][x] = in[(size_t)(row0 + r0 + r) * ld + c0 + x];
    }
    __syncthreads();
    #pragma unroll
    for (int i = 0; i < 4; ++i) {
        int c = y + i * 8;
        float v = tile[x][c];
        unsigned short h, l;
        splitf(v, h, l);
        size_t o = (size_t)(c0 + c) * NR + r0 + x;
        oh[o] = h; ol[o] = l;
    }
}

// ------------------------------------------------------------------
// Split-bf16 MFMA GEMM (NT): C[M,N] = (Ah+Al)[M,K] @ (Bh+Bl)[N,K]^T
// 3-term. Tile 128x128, BK=64, 4 waves.
// MODE bit0: f32 C; bit1: split Ch/Cl; bit2: split TRANSPOSED Ch/Cl
//   (ChT[col][row], leading dim = gridDim.y*128).
// ------------------------------------------------------------------
template<int MODE>
__global__ __launch_bounds__(256, 2) void gemm_nt_mfma(
    const unsigned short* __restrict__ Ah, const unsigned short* __restrict__ Al, int lda,
    const unsigned short* __restrict__ Bh, const unsigned short* __restrict__ Bl, int ldb,
    float* __restrict__ C, unsigned short* __restrict__ Ch, unsigned short* __restrict__ Cl,
    int ldc, int K)
{
    __shared__ __align__(16) unsigned short sAh[128 * 64], sAl[128 * 64];
    __shared__ __align__(16) unsigned short sBh[128 * 64], sBl[128 * 64];
    const int bm = blockIdx.y * 128, bn = blockIdx.x * 128;
    const int t = threadIdx.x;
    const int lane = t & 63, wave = t >> 6;
    const int wr = wave >> 1, wc = wave & 1;
    const int lr = lane & 15;

    f32x4 acc[4][4];
    #pragma unroll
    for (int i = 0; i < 4; ++i)
        #pragma unroll
        for (int j = 0; j < 4; ++j) acc[i][j] = (f32x4){0.f, 0.f, 0.f, 0.f};

    for (int k0 = 0; k0 < K; k0 += 64) {
        __syncthreads();
        #pragma unroll
        for (int i = 0; i < 4; ++i) {
            int idx = t + i * 256;
            int r = idx >> 3, kc = (idx & 7) * 8;
            int off = (r * 128 + kc * 2) ^ ((r & 7) << 4);
            size_t ga = (size_t)(bm + r) * lda + k0 + kc;
            size_t gb = (size_t)(bn + r) * ldb + k0 + kc;
            *(short8*)((char*)sAh + off) = *(const short8*)(Ah + ga);
            *(short8*)((char*)sAl + off) = *(const short8*)(Al + ga);
            *(short8*)((char*)sBh + off) = *(const short8*)(Bh + gb);
            *(short8*)((char*)sBl + off) = *(const short8*)(Bl + gb);
        }
        __syncthreads();
        #pragma unroll
        for (int ks = 0; ks < 2; ++ks) {
            const int kby = ks * 64 + ((lane >> 4) << 4);
            short8 ah[4], al[4];
            #pragma unroll
            for (int rf = 0; rf < 4; ++rf) {
                int row = wr * 64 + rf * 16 + lr;
                int off = (row * 128 + kby) ^ ((row & 7) << 4);
                ah[rf] = *(const short8*)((const char*)sAh + off);
                al[rf] = *(const short8*)((const char*)sAl + off);
            }
            #pragma unroll
            for (int cf = 0; cf < 4; ++cf) {
                int col = wc * 64 + cf * 16 + lr;
                int off = (col * 128 + kby) ^ ((col & 7) << 4);
                short8 bh = *(const short8*)((const char*)sBh + off);
                short8 bl = *(const short8*)((const char*)sBl + off);
                #pragma unroll
                for (int rf = 0; rf < 4; ++rf) {
                    acc[rf][cf] = __builtin_amdgcn_mfma_f32_16x16x32_bf16(ah[rf], bh, acc[rf][cf], 0, 0, 0);
                    acc[rf][cf] = __builtin_amdgcn_mfma_f32_16x16x32_bf16(ah[rf], bl, acc[rf][cf], 0, 0, 0);
                    acc[rf][cf] = __builtin_amdgcn_mfma_f32_16x16x32_bf16(al[rf], bh, acc[rf][cf], 0, 0, 0);
                }
            }
        }
    }
    const int ldt = gridDim.y * 128;
    #pragma unroll
    for (int rf = 0; rf < 4; ++rf) {
        #pragma unroll
        for (int j = 0; j < 4; ++j) {
            int row = bm + wr * 64 + rf * 16 + ((lane >> 4) << 2) + j;
            #pragma unroll
            for (int cf = 0; cf < 4; ++cf) {
                int col = bn + wc * 64 + cf * 16 + lr;
                float v = acc[rf][cf][j];
                size_t o = (size_t)row * ldc + col;
                if (MODE & 1) C[o] = v;
                if (MODE & 2) { unsigned short h, l; splitf(v, h, l); Ch[o] = h; Cl[o] = l; }
                if (MODE & 4) {
                    unsigned short h, l; splitf(v, h, l);
                    size_t ot = (size_t)col * ldt + row;
                    Ch[ot] = h; Cl[ot] = l;
                }
            }
        }
    }
}

// ------------------------------------------------------------------
// MFMA attention core, v2.
// O[b][q][c] = softmax(S)[q][k] @ (Vp[k][c] + Tv[tok_k][c]) decomposed as:
//   P @ Vp   -> per-tile MFMA with VpT (pre-split, pre-transposed, streamed)
//   P binned by token into W[64][128] (f32, LDS) -> epilogue W @ TvT MFMA.
// Scores from 4 precomputed f32 tables (unchanged).
// LDS 64B-row swizzle: idx16 = row*4 + (slot ^ ((row>>1)&3))  -> 2-way max.
// Grid (SEQ/64, NB), 256 threads.
// ------------------------------------------------------------------
__global__ __launch_bounds__(256, 2) void attn_mfma(
    const int* __restrict__ tok,
    const float* __restrict__ Gtt, const float* __restrict__ Gtk,
    const float* __restrict__ Gqt, const float* __restrict__ Gqk,
    const unsigned short* __restrict__ VpTh, const unsigned short* __restrict__ VpTl,
    const unsigned short* __restrict__ TvTh, const unsigned short* __restrict__ TvTl,
    const float* __restrict__ beta1,
    float* __restrict__ O)
{
    const int b = blockIdx.y;
    const int q0 = blockIdx.x * 64;
    const int t = threadIdx.x;
    const int lane = t & 63, wave = t >> 6;
    const float c1 = beta1[0] * 1.12890625f;

    __shared__ __align__(16) unsigned short Mh[256 * 32], Ml[256 * 32];  // [c][k]
    __shared__ __align__(16) unsigned short Ph[64 * 32], Pl[64 * 32];    // [q][k]
    __shared__ float Wt[64 * 128];
    __shared__ float m_s[64], l_s[64], rs_s[64];
    __shared__ int tq_s[64], tk_s[32];

    if (t < 64) {
        tq_s[t] = tok[(size_t)b * SEQ + q0 + t];
        m_s[t] = NEG_INF;
        l_s[t] = 0.f;
    }
    #pragma unroll
    for (int i = 0; i < 32; ++i) Wt[t + i * 256] = 0.f;

    f32x4 acc[4][4];
    #pragma unroll
    for (int i = 0; i < 4; ++i)
        #pragma unroll
        for (int j = 0; j < 4; ++j) acc[i][j] = (f32x4){0.f, 0.f, 0.f, 0.f};

    const int qr = t >> 3;           // 0..31
    const int kb4 = (t & 7) * 4;     // 0..28
    const int lr = lane & 15;
    const int ksl = lane >> 4;       // 0..3
    const int mc = t >> 2, msl = t & 3;

    for (int k0 = 0; k0 < q0 + 64; k0 += 32) {
        if (t < 32) tk_s[t] = tok[(size_t)b * SEQ + k0 + t];
        // ---- stage M (Vp part): 256 cols x 32 k, straight vector copy ----
        #pragma unroll
        for (int i = 0; i < 4; ++i) {
            int c = mc + 64 * i;
            int i16 = c * 4 + (msl ^ ((c >> 1) & 3));
            size_t g = (size_t)c * 2048 + k0 + msl * 8;
            *(short8*)((char*)Mh + i16 * 16) = *(const short8*)(VpTh + g);
            *(short8*)((char*)Ml + i16 * 16) = *(const short8*)(VpTl + g);
        }
        __syncthreads();

        int tkv[4];
        #pragma unroll
        for (int j = 0; j < 4; ++j) tkv[j] = tk_s[kb4 + j];

        // ---- scores + wave-parallel online softmax + W binning ----
        #pragma unroll
        for (int rr = 0; rr < 2; ++rr) {
            const int q = qr + rr * 32;
            const int qg = q0 + q;
            const int tq = tq_s[q];
            f32x4 gqk = *(const f32x4*)&Gqk[(size_t)qg * SEQ + k0 + kb4];
            f32x4 gtk = *(const f32x4*)&Gtk[(size_t)tq * SEQ + k0 + kb4];
            float s[4];
            #pragma unroll
            for (int j = 0; j < 4; ++j) {
                int kg = k0 + kb4 + j;
                s[j] = (kg <= qg)
                     ? c1 * (gqk[j] + gtk[j] + Gtt[tq * 128 + tkv[j]] + Gqt[qg * 128 + tkv[j]])
                     : NEG_INF;
            }
            float tmax = fmaxf(fmaxf(s[0], s[1]), fmaxf(s[2], s[3]));
            tmax = fmaxf(tmax, __shfl_xor(tmax, 1));
            tmax = fmaxf(tmax, __shfl_xor(tmax, 2));
            tmax = fmaxf(tmax, __shfl_xor(tmax, 4));
            const float m_old = m_s[q];
            const float mnew = fmaxf(m_old, tmax);
            float p0 = __expf(s[0] - mnew), p1 = __expf(s[1] - mnew);
            float p2 = __expf(s[2] - mnew), p3 = __expf(s[3] - mnew);
            float lsum = p0 + p1 + p2 + p3;
            lsum += __shfl_xor(lsum, 1);
            lsum += __shfl_xor(lsum, 2);
            lsum += __shfl_xor(lsum, 4);
            const float rs = __expf(m_old - mnew);
            unsigned int l01, l23;
            unsigned int h01 = bfpair(p0, p1, l01);
            unsigned int h23 = bfpair(p2, p3, l23);
            int pbyte = q * 64 + (((kb4 >> 3) ^ ((q >> 1) & 3)) << 4) + ((kb4 & 4) << 1);
            *(uint2v*)((char*)Ph + pbyte) = (uint2v){h01, h23};
            *(uint2v*)((char*)Pl + pbyte) = (uint2v){l01, l23};
            if ((t & 7) == 0) {
                m_s[q] = mnew;
                l_s[q] = l_s[q] * rs + lsum;
                rs_s[q] = rs;
            }
            // W row q is owned by this 8-lane group (same wave): rescale then scatter
            float* wr = Wt + q * 128;
            if (rs != 1.f) {
                const int cb = (t & 7) * 16;
                #pragma unroll
                for (int c2 = 0; c2 < 16; ++c2) wr[cb + c2] *= rs;
            }
            atomicAdd(&wr[tkv[0]], p0);
            atomicAdd(&wr[tkv[1]], p1);
            atomicAdd(&wr[tkv[2]], p2);
            atomicAdd(&wr[tkv[3]], p3);
        }
        __syncthreads();

        // ---- rescale acc + MFMA P@Vp ----
        short8 pah[4], pal[4];
        f32x4 rsv[4];
        #pragma unroll
        for (int qf = 0; qf < 4; ++qf) {
            int row = qf * 16 + lr;
            int i16 = row * 4 + (ksl ^ ((row >> 1) & 3));
            pah[qf] = *(const short8*)((const char*)Ph + i16 * 16);
            pal[qf] = *(const short8*)((const char*)Pl + i16 * 16);
            rsv[qf] = *(const f32x4*)&rs_s[qf * 16 + ksl * 4];
        }
        #pragma unroll
        for (int qf = 0; qf < 4; ++qf)
            #pragma unroll
            for (int cf = 0; cf < 4; ++cf)
                #pragma unroll
                for (int j = 0; j < 4; ++j)
                    acc[qf][cf][j] *= rsv[qf][j];
        #pragma unroll
        for (int cf = 0; cf < 4; ++cf) {
            int col = wave * 64 + cf * 16 + lr;
            int i16 = col * 4 + (ksl ^ ((col >> 1) & 3));
            short8 bh = *(const short8*)((const char*)Mh + i16 * 16);
            short8 bl = *(const short8*)((const char*)Ml + i16 * 16);
            #pragma unroll
            for (int qf = 0; qf < 4; ++qf) {
                acc[qf][cf] = __builtin_amdgcn_mfma_f32_16x16x32_bf16(pah[qf], bh, acc[qf][cf], 0, 0, 0);
                acc[qf][cf] = __builtin_amdgcn_mfma_f32_16x16x32_bf16(pah[qf], bl, acc[qf][cf], 0, 0, 0);
                acc[qf][cf] = __builtin_amdgcn_mfma_f32_16x16x32_bf16(pal[qf], bh, acc[qf][cf], 0, 0, 0);
            }
        }
        __syncthreads();
    }

    // ---- epilogue: token part  W[64][128] @ TvT[256][128]^T(k=t) ----
    #pragma unroll
    for (int ks = 0; ks < 4; ++ks) {
        short8 wh[4], wl[4];
        #pragma unroll
        for (int qf = 0; qf < 4; ++qf) {
            int row = qf * 16 + lr;
            const float* wp = Wt + row * 128 + ks * 32 + ksl * 8;
            unsigned int hh[4], ll[4];
            #pragma unroll
            for (int p2 = 0; p2 < 4; ++p2)
                hh[p2] = bfpair(wp[p2 * 2], wp[p2 * 2 + 1], ll[p2]);
            union { uint4v u; short8 s; } cvh, cvl;
            cvh.u = (uint4v){hh[0], hh[1], hh[2], hh[3]};
            cvl.u = (uint4v){ll[0], ll[1], ll[2], ll[3]};
            wh[qf] = cvh.s; wl[qf] = cvl.s;
        }
        #pragma unroll
        for (int cf = 0; cf < 4; ++cf) {
            int col = wave * 64 + cf * 16 + lr;
            size_t gb = (size_t)col * 128 + ks * 32 + ksl * 8;
            short8 th = *(const short8*)(TvTh + gb);
            short8 tl = *(const short8*)(TvTl + gb);
            #pragma unroll
            for (int qf = 0; qf < 4; ++qf) {
                acc[qf][cf] = __builtin_amdgcn_mfma_f32_16x16x32_bf16(wh[qf], th, acc[qf][cf], 0, 0, 0);
                acc[qf][cf] = __builtin_amdgcn_mfma_f32_16x16x32_bf16(wh[qf], tl, acc[qf][cf], 0, 0, 0);
                acc[qf][cf] = __builtin_amdgcn_mfma_f32_16x16x32_bf16(wl[qf], th, acc[qf][cf], 0, 0, 0);
            }
        }
    }

    // ---- normalize + write O ----
    #pragma unroll
    for (int qf = 0; qf < 4; ++qf) {
        f32x4 lv = *(const f32x4*)&l_s[qf * 16 + ksl * 4];
        f32x4 inv;
        #pragma unroll
        for (int j = 0; j < 4; ++j) inv[j] = 1.0f / lv[j];
        #pragma unroll
        for (int j = 0; j < 4; ++j) {
            int row = q0 + qf * 16 + ksl * 4 + j;
            size_t base = ((size_t)b * SEQ + row) * 256 + wave * 64 + lr;
            #pragma unroll
            for (int cf = 0; cf < 4; ++cf)
                O[base + cf * 16] = acc[qf][cf][j] * inv[j];
        }
    }
}

// ------------------------------------------------------------------
// block reduce helpers
// ------------------------------------------------------------------
__device__ __forceinline__ float blk_reduce_max(float v, float* red, int t)
{
    red[t] = v; __syncthreads();
    #pragma unroll
    for (int s = 128; s >= 1; s >>= 1) {
        if (t < s) red[t] = fmaxf(red[t], red[t + s]);
        __syncthreads();
    }
    float r = red[0]; __syncthreads(); return r;
}
__device__ __forceinline__ float blk_reduce_sum(float v, float* red, int t)
{
    red[t] = v; __syncthreads();
    #pragma unroll
    for (int s = 128; s >= 1; s >>= 1) {
        if (t < s) red[t] += red[t + s];
        __syncthreads();
    }
    float r = red[0]; __syncthreads(); return r;
}

// ------------------------------------------------------------------
// Stage-2 P1: per-batch last-row attention weights a1[b][s] and
// token-binned weights w[b][t]. Grid (NB), 256 threads.
// ------------------------------------------------------------------
__global__ __launch_bounds__(256) void s2_p1(
    const int* __restrict__ tok,
    const float* __restrict__ Gtt, const float* __restrict__ Gtk,
    const float* __restrict__ Gqt, const float* __restrict__ Gqk,
    const float* __restrict__ beta1,
    float* __restrict__ a1g, float* __restrict__ wg)
{
    const int b = blockIdx.x;
    const int t = threadIdx.x;
    const float c1 = beta1[0] * 1.12890625f;

    __shared__ float a_s[SEQ];
    __shared__ float red_s[256];
    __shared__ float w_s[VOC];

    const int* tokb = tok + (size_t)b * SEQ;
    const int tq = tokb[SEQ - 1];

    float lmax = NEG_INF;
    for (int i = t; i < SEQ; i += 256) {
        int tk = tokb[i];
        float s = c1 * (Gtt[tq * 128 + tk] + Gtk[(size_t)tq * SEQ + i]
                      + Gqt[(SEQ - 1) * 128 + tk] + Gqk[(size_t)(SEQ - 1) * SEQ + i]);
        a_s[i] = s;
        lmax = fmaxf(lmax, s);
    }
    float m = blk_reduce_max(lmax, red_s, t);
    float lsum = 0.f;
    for (int i = t; i < SEQ; i += 256) {
        float e = __expf(a_s[i] - m);
        a_s[i] = e;
        lsum += e;
    }
    float l = blk_reduce_sum(lsum, red_s, t);
    float inv = 1.f / l;
    if (t < VOC) w_s[t] = 0.f;
    __syncthreads();
    for (int i = t; i < SEQ; i += 256) {
        float a = a_s[i] * inv;
        a1g[(size_t)b * SEQ + i] = a;
        atomicAdd(&w_s[tokb[i]], a);
    }
    __syncthreads();
    if (t < VOC) wg[b * VOC + t] = w_s[t];
}

// ------------------------------------------------------------------
// Stage-2 P2: q2[b][v]. Grid (NB), 256 threads.
// ------------------------------------------------------------------
__global__ __launch_bounds__(256) void s2_q2k(
    const int* __restrict__ tok, const float* __restrict__ a1g,
    const float* __restrict__ wg, const float* __restrict__ VpQ,
    const float* __restrict__ TvQ, const float* __restrict__ TxQ,
    const float* __restrict__ plq, float* __restrict__ q2)
{
    const int b = blockIdx.x, t = threadIdx.x;
    const int v = t & 127, half = t >> 7;
    __shared__ float red[256];
    const float* a1b = a1g + (size_t)b * SEQ;
    float acc = 0.f;
    for (int i = 0; i < 1024; ++i) {
        int s = half * 1024 + i;
        acc += a1b[s] * VpQ[(size_t)s * VOC + v];
    }
    if (half == 0) {
        const float* wb = wg + b * VOC;
        for (int tt = 0; tt < VOC; ++tt)
            acc += wb[tt] * TvQ[tt * VOC + v];
    }
    red[t] = acc; __syncthreads();
    if (t < VOC) {
        int tq = tok[(size_t)b * SEQ + SEQ - 1];
        q2[b * VOC + t] = red[t] + red[t + 128] + TxQ[tq * VOC + t] + plq[t];
    }
}

// ------------------------------------------------------------------
// Stage-2 P3a: split-flash over s. Grid (8, NB), 256 threads.
// ------------------------------------------------------------------
__global__ __launch_bounds__(256) void s2_p3a(
    const int* __restrict__ tok, const float* __restrict__ q2,
    const float* __restrict__ TxK, const float* __restrict__ PxK,
    const float* __restrict__ TxV, const float* __restrict__ PxV,
    const float* __restrict__ O, const float* __restrict__ beta2,
    float* __restrict__ part)
{
    const int b = blockIdx.y, c = blockIdx.x, t = threadIdx.x;
    const int s0 = c * 256;
    const float c2 = beta2[0] * 289.0f;

    __shared__ float q2s[VOC];
    __shared__ int   toks[256];
    __shared__ float es[256];
    __shared__ float red[256];

    if (t < VOC) q2s[t] = q2[b * VOC + t] * c2;
    toks[t] = tok[(size_t)b * SEQ + s0 + t];
    __syncthreads();

    const int s = s0 + t;
    const float* ok = O + ((size_t)b * SEQ + s) * 256;
    const float* xk = TxK + toks[t] * VOC;
    const float* pk = PxK + (size_t)s * VOC;
    float dot = 0.f;
    #pragma unroll 8
    for (int v = 0; v < VOC; v += 4) {
        f32x4 a = *(const f32x4*)(ok + v);
        f32x4 x = *(const f32x4*)(xk + v);
        f32x4 p = *(const f32x4*)(pk + v);
        f32x4 q = *(const f32x4*)(q2s + v);
        dot += q[0] * (a[0] + x[0] + p[0]) + q[1] * (a[1] + x[1] + p[1])
             + q[2] * (a[2] + x[2] + p[2]) + q[3] * (a[3] + x[3] + p[3]);
    }
    float m = blk_reduce_max(dot, red, t);
    float e = __expf(dot - m);
    es[t] = e;
    float lsum = blk_reduce_sum(e, red, t);

    const int v = t & 127, half = t >> 7;
    float acc = 0.f;
    for (int i = 0; i < 128; ++i) {
        int si = half * 128 + i;
        float ee = es[si];
        acc += ee * (O[((size_t)b * SEQ + s0 + si) * 256 + 128 + v]
                   + TxV[toks[si] * VOC + v] + PxV[(size_t)(s0 + si) * VOC + v]);
    }
    red[t] = acc; __syncthreads();
    float* pb = part + ((size_t)b * 8 + c) * 132;
    if (t < VOC) pb[t] = red[t] + red[t + 128];
    if (t == 128) { pb[128] = m; pb[129] = lsum; }
}

// ------------------------------------------------------------------
// Stage-2 P3b: combine 8 partials + logits. Grid (NB), 128 threads.
// ------------------------------------------------------------------
__global__ __launch_bounds__(128) void s2_p3b(
    const float* __restrict__ part, const float* __restrict__ emb,
    const float* __restrict__ beta_out, float* __restrict__ out)
{
    const int b = blockIdx.x, t = threadIdx.x;
    const float co = beta_out[0] * 70.09279563550022f;
    __shared__ float y2[VOC];
    const float* pb = part + (size_t)b * 8 * 132;
    float M = NEG_INF;
    #pragma unroll
    for (int c = 0; c < 8; ++c) M = fmaxf(M, pb[c * 132 + 128]);
    float L = 0.f, y = 0.f;
    #pragma unroll
    for (int c = 0; c < 8; ++c) {
        float sc = __expf(pb[c * 132 + 128] - M);
        L += pb[c * 132 + 129] * sc;
        y += pb[c * 132 + t] * sc;
    }
    y2[t] = y / L;
    __syncthreads();
    float g = 0.f;
    #pragma unroll 8
    for (int v = 0; v < VOC; ++v) g += y2[v] * emb[t * VOC + v];
    out[(size_t)b * VOC + t] = co * g;
}

// ------------------------------------------------------------------
// plq[v] = pos[last] @ WQ2_bot.  Grid(1), 128 threads.
// ------------------------------------------------------------------
__global__ __launch_bounds__(128) void plq_k(
    const float* __restrict__ pos, const float* __restrict__ WQ2,
    float* __restrict__ plq)
{
    const int t = threadIdx.x;
    float acc = 0.f;
    for (int d = 0; d < SEQ; ++d)
        acc += pos[(size_t)(SEQ - 1) * SEQ + d] * WQ2[(size_t)(VOC + d) * VOC + t];
    plq[t] = acc;
}

// ------------------------------------------------------------------
extern "C" void kernel_launch(void* const* d_in, const int* in_sizes, int n_in,
                              void* d_out, int out_size, void* d_ws, size_t ws_size,
                              hipStream_t stream)
{
    const int* tok = (const int*)d_in[0];
    const float* emb = (const float*)d_in[1];
    const float* pos = (const float*)d_in[2];
    const float* WQ1 = (const float*)d_in[3];
    const float* WK1 = (const float*)d_in[4];
    const float* WV1 = (const float*)d_in[5];
    const float* WQ2 = (const float*)d_in[6];
    const float* WK2 = (const float*)d_in[7];
    const float* WV2 = (const float*)d_in[8];
    const float* beta1 = (const float*)d_in[9];
    const float* beta2 = (const float*)d_in[10];
    const float* beta_out = (const float*)d_in[11];
    float* out = (float*)d_out;

    if (ws_size < 178651136ull) return;

    char* wsb = (char*)d_ws;
    #define MB_(x) ((size_t)(x) * 1048576ull)
    // Split-buffer region: aliased with O (all splits dead before attn runs)
    unsigned short* posH = (unsigned short*)(wsb + MB_(0));
    unsigned short* posL = (unsigned short*)(wsb + MB_(8));
    unsigned short* WTH  = (unsigned short*)(wsb + MB_(16));
    unsigned short* WTL  = (unsigned short*)(wsb + MB_(25));
    unsigned short* QpH  = (unsigned short*)(wsb + MB_(34));
    unsigned short* QpL  = (unsigned short*)(wsb + MB_(42));
    unsigned short* KpH  = (unsigned short*)(wsb + MB_(50));
    unsigned short* KpL  = (unsigned short*)(wsb + MB_(58));
    unsigned short* VpH  = (unsigned short*)(wsb + MB_(66));
    unsigned short* VpL  = (unsigned short*)(wsb + MB_(75));
    unsigned short* TqH  = (unsigned short*)(wsb + MB_(84));
    unsigned short* TqL  = (unsigned short*)(wsb + MB_(84) + 524288);
    unsigned short* TkH  = (unsigned short*)(wsb + MB_(85));
    unsigned short* TkL  = (unsigned short*)(wsb + MB_(85) + 524288);
    float* O = (float*)(wsb + MB_(0));    // 128 MB, aliases the splits

    float* fp = (float*)(wsb + MB_(128));
    auto take = [&](size_t n) { float* p = fp; fp += n; return p; };
    float* Gqk = take((size_t)2048 * 2048);
    float* Gtk = take((size_t)128 * 2048);
    float* Gqt = take((size_t)2048 * 128);
    float* Gtt = take((size_t)128 * 128);
    float* Tq  = take((size_t)128 * 2048);
    float* Tk  = take((size_t)128 * 2048);
    float* Tv  = take((size_t)128 * 2176);
    float* TxK = take((size_t)128 * 128);
    float* TxV = take((size_t)128 * 128);
    float* TvK = take((size_t)128 * 128);
    float* TvV = take((size_t)128 * 128);
    float* PxK = take((size_t)2048 * 128);
    float* PxV = take((size_t)2048 * 128);
    float* VpQ = take((size_t)2048 * 128);
    float* TvQ = take((size_t)128 * 128);
    float* TxQ = take((size_t)128 * 128);
    float* plq = take((size_t)128);
    float* a1g = take((size_t)NB * 2048);
    float* wg  = take((size_t)NB * 128);
    float* q2  = take((size_t)NB * 128);
    float* part = take((size_t)NB * 8 * 132);
    unsigned short* VpTh = (unsigned short*)take((size_t)256 * 2048 / 2);  // [256][2048] bf16
    unsigned short* VpTl = (unsigned short*)take((size_t)256 * 2048 / 2);
    unsigned short* TvTh = (unsigned short*)take((size_t)256 * 128 / 2);   // [256][128] bf16
    unsigned short* TvTl = (unsigned short*)take((size_t)256 * 128 / 2);

    dim3 blk(256);

    // --- tiny token-table GEMMs (f32) ---
    hipLaunchKernelGGL((gemm_f32<0>), dim3(32, 2), blk, 0, stream, emb, 128, WQ1, 2048, Tq, 2048, 128, 2048, 128);
    hipLaunchKernelGGL((gemm_f32<0>), dim3(32, 2), blk, 0, stream, emb, 128, WK1, 2048, Tk, 2048, 128, 2048, 128);
    hipLaunchKernelGGL((gemm_f32<0>), dim3(34, 2), blk, 0, stream, emb, 128, WV1, 2176, Tv, 2176, 128, 2176, 128);
    hipLaunchKernelGGL((gemm_f32<0>), dim3(2, 2),  blk, 0, stream, emb, 128, WK2, 128, TxK, 128, 128, 128, 128);
    hipLaunchKernelGGL((gemm_f32<0>), dim3(2, 2),  blk, 0, stream, emb, 128, WV2, 128, TxV, 128, 128, 128, 128);
    hipLaunchKernelGGL((gemm_f32<0>), dim3(2, 2),  blk, 0, stream, emb, 128, WQ2, 128, TxQ, 128, 128, 128, 128);
    hipLaunchKernelGGL(plq_k, dim3(1), dim3(128), 0, stream, pos, WQ2, plq);

    // --- splits + big MFMA GEMMs ---
    hipLaunchKernelGGL(split_plain, dim3(4096), blk, 0, stream, pos, posH, posL, 1048576);
    hipLaunchKernelGGL(splitT, dim3(64, 64), blk, 0, stream, WQ1, 2048, 128, 2048, 2048, WTH, WTL);
    hipLaunchKernelGGL((gemm_nt_mfma<2>), dim3(16, 16), blk, 0, stream,
                       posH, posL, 2048, WTH, WTL, 2048, (float*)nullptr, QpH, QpL, 2048, 2048);
    hipLaunchKernelGGL(splitT, dim3(64, 64), blk, 0, stream, WK1, 2048, 128, 2048, 2048, WTH, WTL);
    hipLaunchKernelGGL((gemm_nt_mfma<2>), dim3(16, 16), blk, 0, stream,
                       posH, posL, 2048, WTH, WTL, 2048, (float*)nullptr, KpH, KpL, 2048, 2048);
    hipLaunchKernelGGL(splitT, dim3(64, 68), blk, 0, stream, WV1, 2176, 128, 2048, 2176, WTH, WTL);
    hipLaunchKernelGGL((gemm_nt_mfma<2>), dim3(17, 16), blk, 0, stream,
                       posH, posL, 2048, WTH, WTL, 2048, (float*)nullptr, VpH, VpL, 2176, 2048);
    hipLaunchKernelGGL((gemm_nt_mfma<1>), dim3(16, 16), blk, 0, stream,
                       QpH, QpL, 2048, KpH, KpL, 2048, Gqk, (unsigned short*)nullptr, (unsigned short*)nullptr, 2048, 2048);
    hipLaunchKernelGGL(split_plain, dim3(256), blk, 0, stream, Tq, TqH, TqL, 65536);
    hipLaunchKernelGGL(split_plain, dim3(256), blk, 0, stream, Tk, TkH, TkL, 65536);
    hipLaunchKernelGGL((gemm_nt_mfma<1>), dim3(16, 1), blk, 0, stream,
                       TqH, TqL, 2048, KpH, KpL, 2048, Gtk, (unsigned short*)nullptr, (unsigned short*)nullptr, 2048, 2048);
    hipLaunchKernelGGL((gemm_nt_mfma<1>), dim3(1, 16), blk, 0, stream,
                       QpH, QpL, 2048, TkH, TkL, 2048, Gqt, (unsigned short*)nullptr, (unsigned short*)nullptr, 128, 2048);
    hipLaunchKernelGGL((gemm_nt_mfma<1>), dim3(1, 1), blk, 0, stream,
                       TqH, TqL, 2048, TkH, TkL, 2048, Gtt, (unsigned short*)nullptr, (unsigned short*)nullptr, 128, 2048);
    hipLaunchKernelGGL(splitT, dim3(64, 4), blk, 0, stream, WK2, 128, 128, 2048, 128, WTH, WTL);
    hipLaunchKernelGGL((gemm_nt_mfma<1>), dim3(1, 16), blk, 0, stream,
                       posH, posL, 2048, WTH, WTL, 2048, PxK, (unsigned short*)nullptr, (unsigned short*)nullptr, 128, 2048);
    hipLaunchKernelGGL(splitT, dim3(64, 4), blk, 0, stream, WV2, 128, 128, 2048, 128, WTH, WTL);
    hipLaunchKernelGGL((gemm_nt_mfma<1>), dim3(1, 16), blk, 0, stream,
                       posH, posL, 2048, WTH, WTL, 2048, PxV, (unsigned short*)nullptr, (unsigned short*)nullptr, 128, 2048);
    // Vp projections: K2-part/V2-part -> split TRANSPOSED VpT [256][2048]
    hipLaunchKernelGGL(splitT, dim3(68, 4), blk, 0, stream, WK2, 128, 0, 2176, 128, WTH, WTL);
    hipLaunchKernelGGL((gemm_nt_mfma<4>), dim3(1, 16), blk, 0, stream,
                       VpH, VpL, 2176, WTH, WTL, 2176, (float*)nullptr, VpTh, VpTl, 128, 2176);
    hipLaunchKernelGGL(splitT, dim3(68, 4), blk, 0, stream, WV2, 128, 0, 2176, 128, WTH, WTL);
    hipLaunchKernelGGL((gemm_nt_mfma<4>), dim3(1, 16), blk, 0, stream,
                       VpH, VpL, 2176, WTH, WTL, 2176, (float*)nullptr, VpTh + (size_t)128 * 2048, VpTl + (size_t)128 * 2048, 128, 2176);
    hipLaunchKernelGGL(splitT, dim3(68, 4), blk, 0, stream, WQ2, 128, 0, 2176, 128, WTH, WTL);
    hipLaunchKernelGGL((gemm_nt_mfma<1>), dim3(1, 16), blk, 0, stream,
                       VpH, VpL, 2176, WTH, WTL, 2176, VpQ, (unsigned short*)nullptr, (unsigned short*)nullptr, 128, 2176);
    hipLaunchKernelGGL((gemm_f32<0>), dim3(2, 2), blk, 0, stream, Tv, 2176, WK2, 128, TvK, 128, 128, 128, 2176);
    hipLaunchKernelGGL((gemm_f32<0>), dim3(2, 2), blk, 0, stream, Tv, 2176, WV2, 128, TvV, 128, 128, 128, 2176);
    hipLaunchKernelGGL((gemm_f32<0>), dim3(2, 2), blk, 0, stream, Tv, 2176, WQ2, 128, TvQ, 128, 128, 128, 2176);
    // TvT [256][128] split (transpose of TvK / TvV)
    hipLaunchKernelGGL(splitT, dim3(4, 4), blk, 0, stream, TvK, 128, 0, 128, 128, TvTh, TvTl);
    hipLaunchKernelGGL(splitT, dim3(4, 4), blk, 0, stream, TvV, 128, 0, 128, 128, TvTh + 128 * 128, TvTl + 128 * 128);

    // --- attention core (writes O; splits region is dead by now) ---
    hipLaunchKernelGGL(attn_mfma, dim3(32, 64), blk, 0, stream,
                       tok, Gtt, Gtk, Gqt, Gqk, VpTh, VpTl, TvTh, TvTl, beta1, O);

    // --- stage 2 (parallel decomposition) ---
    hipLaunchKernelGGL(s2_p1, dim3(NB), blk, 0, stream,
                       tok, Gtt, Gtk, Gqt, Gqk, beta1, a1g, wg);
    hipLaunchKernelGGL(s2_q2k, dim3(NB), blk, 0, stream,
                       tok, a1g, wg, VpQ, TvQ, TxQ, plq, q2);
    hipLaunchKernelGGL(s2_p3a, dim3(8, NB), blk, 0, stream,
                       tok, q2, TxK, PxK, TxV, PxV, O, beta2, part);
    hipLaunchKernelGGL(s2_p3b, dim3(NB), dim3(128), 0, stream,
                       part, emb, beta_out, out);
}

// Round 6
// 2403.906 us; speedup vs baseline: 1.5191x; 1.5191x over previous
//
#include <hip/hip_runtime.h>
#include <cmath>

#define SEQ 2048
#define NB 64
#define VOC 128
#define DM 2176
#define NEG_INF -1e30f

typedef __attribute__((ext_vector_type(8))) short short8;
typedef __attribute__((ext_vector_type(4))) float f32x4;
typedef __attribute__((ext_vector_type(4))) unsigned int uint4v;
typedef __attribute__((ext_vector_type(2))) unsigned int uint2v;

// ---------- bf16 split helpers (hi = truncation, lo = remainder) ----------
__device__ __forceinline__ void splitf(float x, unsigned short& h, unsigned short& l) {
    unsigned int u = __float_as_uint(x);
    h = (unsigned short)(u >> 16);
    float d = x - __uint_as_float(u & 0xFFFF0000u);
    l = (unsigned short)(__float_as_uint(d) >> 16);
}
__device__ __forceinline__ unsigned int bfpair(float x0, float x1, unsigned int& lopair) {
    unsigned int u0 = __float_as_uint(x0), u1 = __float_as_uint(x1);
    float d0 = x0 - __uint_as_float(u0 & 0xFFFF0000u);
    float d1 = x1 - __uint_as_float(u1 & 0xFFFF0000u);
    lopair = (__float_as_uint(d0) >> 16) | (__float_as_uint(d1) & 0xFFFF0000u);
    return (u0 >> 16) | (u1 & 0xFFFF0000u);
}

// ------------------------------------------------------------------
// Naive tiled f32 GEMM (tiny GEMMs only). C[M,N] = A[M,K] @ B[K,N].
// ------------------------------------------------------------------
template<int TB>
__global__ __launch_bounds__(256) void gemm_f32(
    const float* __restrict__ A, int lda,
    const float* __restrict__ B, int ldb,
    float* __restrict__ C, int ldc,
    int M, int N, int K)
{
    __shared__ float As[16][64];
    __shared__ float Bs[16][65];
    const int bm = blockIdx.y * 64;
    const int bn = blockIdx.x * 64;
    const int t  = threadIdx.x;
    const int tx = t & 15, ty = t >> 4;
    float acc[4][4] = {};
    for (int k0 = 0; k0 < K; k0 += 16) {
        #pragma unroll
        for (int i = 0; i < 4; ++i) {
            int m = (t >> 4) + 16 * i;
            int k = t & 15;
            As[k][m] = A[(size_t)(bm + m) * lda + k0 + k];
        }
        if (TB == 0) {
            #pragma unroll
            for (int i = 0; i < 4; ++i) {
                int n = t & 63;
                int k = (t >> 6) + 4 * i;
                Bs[k][n] = B[(size_t)(k0 + k) * ldb + bn + n];
            }
        } else {
            #pragma unroll
            for (int i = 0; i < 4; ++i) {
                int k = t & 15;
                int n = (t >> 4) + 16 * i;
                Bs[k][n] = B[(size_t)(bn + n) * ldb + k0 + k];
            }
        }
        __syncthreads();
        #pragma unroll
        for (int kk = 0; kk < 16; ++kk) {
            float a[4], bb[4];
            #pragma unroll
            for (int i = 0; i < 4; ++i) a[i] = As[kk][ty * 4 + i];
            #pragma unroll
            for (int j = 0; j < 4; ++j) bb[j] = Bs[kk][tx * 4 + j];
            #pragma unroll
            for (int i = 0; i < 4; ++i)
                #pragma unroll
                for (int j = 0; j < 4; ++j)
                    acc[i][j] += a[i] * bb[j];
        }
        __syncthreads();
    }
    #pragma unroll
    for (int i = 0; i < 4; ++i) {
        size_t m = bm + ty * 4 + i;
        #pragma unroll
        for (int j = 0; j < 4; ++j)
            C[m * ldc + bn + tx * 4 + j] = acc[i][j];
    }
}

// ------------------------------------------------------------------
__global__ __launch_bounds__(256) void split_plain(
    const float* __restrict__ in, unsigned short* __restrict__ oh,
    unsigned short* __restrict__ ol, int n4)
{
    int i = blockIdx.x * 256 + threadIdx.x;
    if (i >= n4) return;
    f32x4 v = *(const f32x4*)(in + (size_t)i * 4);
    unsigned int h01, h23, l01, l23;
    h01 = bfpair(v[0], v[1], l01);
    h23 = bfpair(v[2], v[3], l23);
    *(uint2v*)(oh + (size_t)i * 4) = (uint2v){h01, h23};
    *(uint2v*)(ol + (size_t)i * 4) = (uint2v){l01, l23};
}

// ------------------------------------------------------------------
// Split + transpose: out[c][r] = in[(row0+r)*ld + c], r<NR, c<NC. out ld = NR.
// Grid (NR/32, NC/32), 256 threads.
// ------------------------------------------------------------------
__global__ __launch_bounds__(256) void splitT(
    const float* __restrict__ in, int ld, int row0,
    int NR, int NC,
    unsigned short* __restrict__ oh, unsigned short* __restrict__ ol)
{
    __shared__ float tile[32][33];
    const int r0 = blockIdx.x * 32, c0 = blockIdx.y * 32;
    const int t = threadIdx.x;
    const int x = t & 31, y = t >> 5;
    #pragma unroll
    for (int i = 0; i < 4; ++i) {
        int r = y + i * 8;
        tile[r][x] = in[(size_t)(row0 + r0 + r) * ld + c0 + x];
    }
    __syncthreads();
    #pragma unroll
    for (int i = 0; i < 4; ++i) {
        int c = y + i * 8;
        float v = tile[x][c];
        unsigned short h, l;
        splitf(v, h, l);
        size_t o = (size_t)(c0 + c) * NR + r0 + x;
        oh[o] = h; ol[o] = l;
    }
}

// ------------------------------------------------------------------
// Split-bf16 MFMA GEMM (NT): C[M,N] = (Ah+Al)[M,K] @ (Bh+Bl)[N,K]^T
// 3-term. Tile 128x128, BK=64, 4 waves. MODE bit0: f32 C; bit1: split Ch/Cl.
// ------------------------------------------------------------------
template<int MODE>
__global__ __launch_bounds__(256, 2) void gemm_nt_mfma(
    const unsigned short* __restrict__ Ah, const unsigned short* __restrict__ Al, int lda,
    const unsigned short* __restrict__ Bh, const unsigned short* __restrict__ Bl, int ldb,
    float* __restrict__ C, unsigned short* __restrict__ Ch, unsigned short* __restrict__ Cl,
    int ldc, int K)
{
    __shared__ __align__(16) unsigned short sAh[128 * 64], sAl[128 * 64];
    __shared__ __align__(16) unsigned short sBh[128 * 64], sBl[128 * 64];
    const int bm = blockIdx.y * 128, bn = blockIdx.x * 128;
    const int t = threadIdx.x;
    const int lane = t & 63, wave = t >> 6;
    const int wr = wave >> 1, wc = wave & 1;
    const int lr = lane & 15;

    f32x4 acc[4][4];
    #pragma unroll
    for (int i = 0; i < 4; ++i)
        #pragma unroll
        for (int j = 0; j < 4; ++j) acc[i][j] = (f32x4){0.f, 0.f, 0.f, 0.f};

    for (int k0 = 0; k0 < K; k0 += 64) {
        __syncthreads();
        #pragma unroll
        for (int i = 0; i < 4; ++i) {
            int idx = t + i * 256;
            int r = idx >> 3, kc = (idx & 7) * 8;
            int off = (r * 128 + kc * 2) ^ ((r & 7) << 4);
            size_t ga = (size_t)(bm + r) * lda + k0 + kc;
            size_t gb = (size_t)(bn + r) * ldb + k0 + kc;
            *(short8*)((char*)sAh + off) = *(const short8*)(Ah + ga);
            *(short8*)((char*)sAl + off) = *(const short8*)(Al + ga);
            *(short8*)((char*)sBh + off) = *(const short8*)(Bh + gb);
            *(short8*)((char*)sBl + off) = *(const short8*)(Bl + gb);
        }
        __syncthreads();
        #pragma unroll
        for (int ks = 0; ks < 2; ++ks) {
            const int kby = ks * 64 + ((lane >> 4) << 4);
            short8 ah[4], al[4];
            #pragma unroll
            for (int rf = 0; rf < 4; ++rf) {
                int row = wr * 64 + rf * 16 + lr;
                int off = (row * 128 + kby) ^ ((row & 7) << 4);
                ah[rf] = *(const short8*)((const char*)sAh + off);
                al[rf] = *(const short8*)((const char*)sAl + off);
            }
            #pragma unroll
            for (int cf = 0; cf < 4; ++cf) {
                int col = wc * 64 + cf * 16 + lr;
                int off = (col * 128 + kby) ^ ((col & 7) << 4);
                short8 bh = *(const short8*)((const char*)sBh + off);
                short8 bl = *(const short8*)((const char*)sBl + off);
                #pragma unroll
                for (int rf = 0; rf < 4; ++rf) {
                    acc[rf][cf] = __builtin_amdgcn_mfma_f32_16x16x32_bf16(ah[rf], bh, acc[rf][cf], 0, 0, 0);
                    acc[rf][cf] = __builtin_amdgcn_mfma_f32_16x16x32_bf16(ah[rf], bl, acc[rf][cf], 0, 0, 0);
                    acc[rf][cf] = __builtin_amdgcn_mfma_f32_16x16x32_bf16(al[rf], bh, acc[rf][cf], 0, 0, 0);
                }
            }
        }
    }
    #pragma unroll
    for (int rf = 0; rf < 4; ++rf) {
        #pragma unroll
        for (int j = 0; j < 4; ++j) {
            int row = bm + wr * 64 + rf * 16 + ((lane >> 4) << 2) + j;
            #pragma unroll
            for (int cf = 0; cf < 4; ++cf) {
                int col = bn + wc * 64 + cf * 16 + lr;
                float v = acc[rf][cf][j];
                size_t o = (size_t)row * ldc + col;
                if (MODE & 1) C[o] = v;
                if (MODE & 2) { unsigned short h, l; splitf(v, h, l); Ch[o] = h; Cl[o] = l; }
            }
        }
    }
}

// ------------------------------------------------------------------
// MFMA attention core, v3 (round-3 structure + GT token-score LDS table
// + corrected LDS swizzle for the 64B-row M/P tiles).
// M[c][k] = TvX[tok_k][c] + VpKVQ[k][c-part]; P from 4 tables with GT.
// Swizzle: idx16(row, slot) = row*4 + ((slot + (row>>1)) & 3)
//   -> every 8-lane phase of b128/b64 LDS ops hits 8 distinct bank groups.
// Grid (SEQ/64, NB), 256 threads.
// ------------------------------------------------------------------
__global__ __launch_bounds__(256, 2) void attn_mfma(
    const int* __restrict__ tok,
    const float* __restrict__ Gtt, const float* __restrict__ Gtk,
    const float* __restrict__ Gqt, const float* __restrict__ Gqk,
    const float* __restrict__ TvK, const float* __restrict__ TvV,
    const float* __restrict__ VpKVQ,
    const float* __restrict__ beta1,
    float* __restrict__ O)
{
    const int b = blockIdx.y;
    const int q0 = blockIdx.x * 64;
    const int t = threadIdx.x;
    const int lane = t & 63, wave = t >> 6;
    const float c1 = beta1[0] * 1.12890625f;

    __shared__ __align__(16) unsigned short Mh[256 * 32], Ml[256 * 32];  // [c][k]
    __shared__ __align__(16) unsigned short Ph[64 * 32], Pl[64 * 32];    // [q][k]
    __shared__ float GT[64 * 128];
    __shared__ float m_s[64], l_s[64], rs_s[64];
    __shared__ int tq_s[64], tk_s[32];

    if (t < 64) {
        tq_s[t] = tok[(size_t)b * SEQ + q0 + t];
        m_s[t] = NEG_INF;
        l_s[t] = 0.f;
    }
    __syncthreads();
    // ---- GT[q][tk] = Gqt[q0+q][tk] + Gtt[tq_q][tk] (one coalesced pass) ----
    {
        const int c4 = (t & 31) * 4;
        #pragma unroll
        for (int i = 0; i < 8; ++i) {
            int q = (t >> 5) + i * 8;
            f32x4 a = *(const f32x4*)&Gqt[(size_t)(q0 + q) * 128 + c4];
            f32x4 g = *(const f32x4*)&Gtt[(size_t)tq_s[q] * 128 + c4];
            *(f32x4*)&GT[q * 128 + c4] = a + g;
        }
    }

    f32x4 acc[4][4];
    #pragma unroll
    for (int i = 0; i < 4; ++i)
        #pragma unroll
        for (int j = 0; j < 4; ++j) acc[i][j] = (f32x4){0.f, 0.f, 0.f, 0.f};

    const int qr = t >> 3;           // 0..31
    const int kb4 = (t & 7) * 4;     // 0..28
    const int lr = lane & 15;
    const int ksl = lane >> 4;       // 0..3
    const int cc = t & 127;
    const float* Tb = (t < 128) ? TvK : TvV;
    const float* Vb = VpKVQ + ((t < 128) ? 0 : 128);

    for (int k0 = 0; k0 <= q0 + 32; k0 += 32) {
        if (t < 32) tk_s[t] = tok[(size_t)b * SEQ + k0 + t];
        __syncthreads();   // tk_s visible; prev MFMA done before M/P overwrite

        // ---- build M: thread owns column cc of its half; 4 granules ----
        #pragma unroll
        for (int g = 0; g < 4; ++g) {
            unsigned int hh[4], ll[4];
            #pragma unroll
            for (int p = 0; p < 4; ++p) {
                int kk = g * 8 + p * 2;
                float x0 = Tb[tk_s[kk] * 128 + cc]     + Vb[(size_t)(k0 + kk) * 384 + cc];
                float x1 = Tb[tk_s[kk + 1] * 128 + cc] + Vb[(size_t)(k0 + kk + 1) * 384 + cc];
                hh[p] = bfpair(x0, x1, ll[p]);
            }
            int i16 = t * 4 + ((g + (t >> 1)) & 3);
            *(uint4v*)((char*)Mh + i16 * 16) = (uint4v){hh[0], hh[1], hh[2], hh[3]};
            *(uint4v*)((char*)Ml + i16 * 16) = (uint4v){ll[0], ll[1], ll[2], ll[3]};
        }

        // ---- scores + wave-parallel online softmax (2 q-rows/thread) ----
        #pragma unroll
        for (int rr = 0; rr < 2; ++rr) {
            const int q = qr + rr * 32;
            const int qg = q0 + q;
            f32x4 gqk = *(const f32x4*)&Gqk[(size_t)qg * SEQ + k0 + kb4];
            f32x4 gtk = *(const f32x4*)&Gtk[(size_t)tq_s[q] * SEQ + k0 + kb4];
            float s[4];
            #pragma unroll
            for (int j = 0; j < 4; ++j) {
                int kg = k0 + kb4 + j;
                s[j] = (kg <= qg)
                     ? c1 * (gqk[j] + gtk[j] + GT[q * 128 + tk_s[kb4 + j]])
                     : NEG_INF;
            }
            float tmax = fmaxf(fmaxf(s[0], s[1]), fmaxf(s[2], s[3]));
            tmax = fmaxf(tmax, __shfl_xor(tmax, 1));
            tmax = fmaxf(tmax, __shfl_xor(tmax, 2));
            tmax = fmaxf(tmax, __shfl_xor(tmax, 4));
            const float m_old = m_s[q];
            const float mnew = fmaxf(m_old, tmax);
            float p0 = __expf(s[0] - mnew), p1 = __expf(s[1] - mnew);
            float p2 = __expf(s[2] - mnew), p3 = __expf(s[3] - mnew);
            float lsum = p0 + p1 + p2 + p3;
            lsum += __shfl_xor(lsum, 1);
            lsum += __shfl_xor(lsum, 2);
            lsum += __shfl_xor(lsum, 4);
            unsigned int l01, l23;
            unsigned int h01 = bfpair(p0, p1, l01);
            unsigned int h23 = bfpair(p2, p3, l23);
            int i16 = q * 4 + (((kb4 >> 3) + (q >> 1)) & 3);
            int pbyte = i16 * 16 + ((kb4 & 4) << 1);
            *(uint2v*)((char*)Ph + pbyte) = (uint2v){h01, h23};
            *(uint2v*)((char*)Pl + pbyte) = (uint2v){l01, l23};
            if ((t & 7) == 0) {
                float rs = __expf(m_old - mnew);
                m_s[q] = mnew;
                l_s[q] = l_s[q] * rs + lsum;
                rs_s[q] = rs;
            }
        }
        __syncthreads();

        // ---- rescale acc + MFMA P@M ----
        short8 pah[4], pal[4];
        f32x4 rsv[4];
        #pragma unroll
        for (int qf = 0; qf < 4; ++qf) {
            int row = qf * 16 + lr;
            int i16 = row * 4 + ((ksl + (row >> 1)) & 3);
            pah[qf] = *(const short8*)((const char*)Ph + i16 * 16);
            pal[qf] = *(const short8*)((const char*)Pl + i16 * 16);
            rsv[qf] = *(const f32x4*)&rs_s[qf * 16 + ksl * 4];
        }
        #pragma unroll
        for (int qf = 0; qf < 4; ++qf)
            #pragma unroll
            for (int cf = 0; cf < 4; ++cf)
                #pragma unroll
                for (int j = 0; j < 4; ++j)
                    acc[qf][cf][j] *= rsv[qf][j];
        #pragma unroll
        for (int cf = 0; cf < 4; ++cf) {
            int col = wave * 64 + cf * 16 + lr;
            int i16 = col * 4 + ((ksl + (col >> 1)) & 3);
            short8 bh = *(const short8*)((const char*)Mh + i16 * 16);
            short8 bl = *(const short8*)((const char*)Ml + i16 * 16);
            #pragma unroll
            for (int qf = 0; qf < 4; ++qf) {
                acc[qf][cf] = __builtin_amdgcn_mfma_f32_16x16x32_bf16(pah[qf], bh, acc[qf][cf], 0, 0, 0);
                acc[qf][cf] = __builtin_amdgcn_mfma_f32_16x16x32_bf16(pah[qf], bl, acc[qf][cf], 0, 0, 0);
                acc[qf][cf] = __builtin_amdgcn_mfma_f32_16x16x32_bf16(pal[qf], bh, acc[qf][cf], 0, 0, 0);
            }
        }
    }
    // ---- epilogue: divide by l, write O ----
    #pragma unroll
    for (int qf = 0; qf < 4; ++qf) {
        f32x4 lv = *(const f32x4*)&l_s[qf * 16 + ksl * 4];
        f32x4 inv;
        #pragma unroll
        for (int j = 0; j < 4; ++j) inv[j] = 1.0f / lv[j];
        #pragma unroll
        for (int j = 0; j < 4; ++j) {
            int row = q0 + qf * 16 + ksl * 4 + j;
            size_t base = ((size_t)b * SEQ + row) * 256 + wave * 64 + lr;
            #pragma unroll
            for (int cf = 0; cf < 4; ++cf)
                O[base + cf * 16] = acc[qf][cf][j] * inv[j];
        }
    }
}

// ------------------------------------------------------------------
// block reduce helpers
// ------------------------------------------------------------------
__device__ __forceinline__ float blk_reduce_max(float v, float* red, int t)
{
    red[t] = v; __syncthreads();
    #pragma unroll
    for (int s = 128; s >= 1; s >>= 1) {
        if (t < s) red[t] = fmaxf(red[t], red[t + s]);
        __syncthreads();
    }
    float r = red[0]; __syncthreads(); return r;
}
__device__ __forceinline__ float blk_reduce_sum(float v, float* red, int t)
{
    red[t] = v; __syncthreads();
    #pragma unroll
    for (int s = 128; s >= 1; s >>= 1) {
        if (t < s) red[t] += red[t + s];
        __syncthreads();
    }
    float r = red[0]; __syncthreads(); return r;
}

// ------------------------------------------------------------------
// Stage-2 P1: per-batch last-row attention weights a1[b][s] and
// token-binned weights w[b][t]. Grid (NB), 256 threads.
// ------------------------------------------------------------------
__global__ __launch_bounds__(256) void s2_p1(
    const int* __restrict__ tok,
    const float* __restrict__ Gtt, const float* __restrict__ Gtk,
    const float* __restrict__ Gqt, const float* __restrict__ Gqk,
    const float* __restrict__ beta1,
    float* __restrict__ a1g, float* __restrict__ wg)
{
    const int b = blockIdx.x;
    const int t = threadIdx.x;
    const float c1 = beta1[0] * 1.12890625f;

    __shared__ float a_s[SEQ];
    __shared__ float red_s[256];
    __shared__ float w_s[VOC];

    const int* tokb = tok + (size_t)b * SEQ;
    const int tq = tokb[SEQ - 1];

    float lmax = NEG_INF;
    for (int i = t; i < SEQ; i += 256) {
        int tk = tokb[i];
        float s = c1 * (Gtt[tq * 128 + tk] + Gtk[(size_t)tq * SEQ + i]
                      + Gqt[(SEQ - 1) * 128 + tk] + Gqk[(size_t)(SEQ - 1) * SEQ + i]);
        a_s[i] = s;
        lmax = fmaxf(lmax, s);
    }
    float m = blk_reduce_max(lmax, red_s, t);
    float lsum = 0.f;
    for (int i = t; i < SEQ; i += 256) {
        float e = __expf(a_s[i] - m);
        a_s[i] = e;
        lsum += e;
    }
    float l = blk_reduce_sum(lsum, red_s, t);
    float inv = 1.f / l;
    if (t < VOC) w_s[t] = 0.f;
    __syncthreads();
    for (int i = t; i < SEQ; i += 256) {
        float a = a_s[i] * inv;
        a1g[(size_t)b * SEQ + i] = a;
        atomicAdd(&w_s[tokb[i]], a);
    }
    __syncthreads();
    if (t < VOC) wg[b * VOC + t] = w_s[t];
}

// ------------------------------------------------------------------
// Stage-2 P2: q2[b][v]. Grid (NB), 256 threads.  VpQ is cols 256..383 of VpKVQ.
// ------------------------------------------------------------------
__global__ __launch_bounds__(256) void s2_q2k(
    const int* __restrict__ tok, const float* __restrict__ a1g,
    const float* __restrict__ wg, const float* __restrict__ VpKVQ,
    const float* __restrict__ TvQ, const float* __restrict__ TxQ,
    const float* __restrict__ plq, float* __restrict__ q2)
{
    const int b = blockIdx.x, t = threadIdx.x;
    const int v = t & 127, half = t >> 7;
    __shared__ float red[256];
    const float* a1b = a1g + (size_t)b * SEQ;
    float acc = 0.f;
    for (int i = 0; i < 1024; ++i) {
        int s = half * 1024 + i;
        acc += a1b[s] * VpKVQ[(size_t)s * 384 + 256 + v];
    }
    if (half == 0) {
        const float* wb = wg + b * VOC;
        for (int tt = 0; tt < VOC; ++tt)
            acc += wb[tt] * TvQ[tt * VOC + v];
    }
    red[t] = acc; __syncthreads();
    if (t < VOC) {
        int tq = tok[(size_t)b * SEQ + SEQ - 1];
        q2[b * VOC + t] = red[t] + red[t + 128] + TxQ[tq * VOC + t] + plq[t];
    }
}

// ------------------------------------------------------------------
// Stage-2 P3a: split-flash over s. Grid (8, NB), 256 threads.
// PxKV: [s][256] (K part cols 0..127, V part 128..255).
// ------------------------------------------------------------------
__global__ __launch_bounds__(256) void s2_p3a(
    const int* __restrict__ tok, const float* __restrict__ q2,
    const float* __restrict__ TxK, const float* __restrict__ PxKV,
    const float* __restrict__ TxV,
    const float* __restrict__ O, const float* __restrict__ beta2,
    float* __restrict__ part)
{
    const int b = blockIdx.y, c = blockIdx.x, t = threadIdx.x;
    const int s0 = c * 256;
    const float c2 = beta2[0] * 289.0f;

    __shared__ float q2s[VOC];
    __shared__ int   toks[256];
    __shared__ float es[256];
    __shared__ float red[256];

    if (t < VOC) q2s[t] = q2[b * VOC + t] * c2;
    toks[t] = tok[(size_t)b * SEQ + s0 + t];
    __syncthreads();

    const int s = s0 + t;
    const float* ok = O + ((size_t)b * SEQ + s) * 256;
    const float* xk = TxK + toks[t] * VOC;
    const float* pk = PxKV + (size_t)s * 256;
    float dot = 0.f;
    #pragma unroll 8
    for (int v = 0; v < VOC; v += 4) {
        f32x4 a = *(const f32x4*)(ok + v);
        f32x4 x = *(const f32x4*)(xk + v);
        f32x4 p = *(const f32x4*)(pk + v);
        f32x4 q = *(const f32x4*)(q2s + v);
        dot += q[0] * (a[0] + x[0] + p[0]) + q[1] * (a[1] + x[1] + p[1])
             + q[2] * (a[2] + x[2] + p[2]) + q[3] * (a[3] + x[3] + p[3]);
    }
    float m = blk_reduce_max(dot, red, t);
    float e = __expf(dot - m);
    es[t] = e;
    float lsum = blk_reduce_sum(e, red, t);

    const int v = t & 127, half = t >> 7;
    float acc = 0.f;
    for (int i = 0; i < 128; ++i) {
        int si = half * 128 + i;
        float ee = es[si];
        acc += ee * (O[((size_t)b * SEQ + s0 + si) * 256 + 128 + v]
                   + TxV[toks[si] * VOC + v] + PxKV[(size_t)(s0 + si) * 256 + 128 + v]);
    }
    red[t] = acc; __syncthreads();
    float* pb = part + ((size_t)b * 8 + c) * 132;
    if (t < VOC) pb[t] = red[t] + red[t + 128];
    if (t == 128) { pb[128] = m; pb[129] = lsum; }
}

// ------------------------------------------------------------------
// Stage-2 P3b: combine 8 partials + logits. Grid (NB), 128 threads.
// ------------------------------------------------------------------
__global__ __launch_bounds__(128) void s2_p3b(
    const float* __restrict__ part, const float* __restrict__ emb,
    const float* __restrict__ beta_out, float* __restrict__ out)
{
    const int b = blockIdx.x, t = threadIdx.x;
    const float co = beta_out[0] * 70.09279563550022f;
    __shared__ float y2[VOC];
    const float* pb = part + (size_t)b * 8 * 132;
    float M = NEG_INF;
    #pragma unroll
    for (int c = 0; c < 8; ++c) M = fmaxf(M, pb[c * 132 + 128]);
    float L = 0.f, y = 0.f;
    #pragma unroll
    for (int c = 0; c < 8; ++c) {
        float sc = __expf(pb[c * 132 + 128] - M);
        L += pb[c * 132 + 129] * sc;
        y += pb[c * 132 + t] * sc;
    }
    y2[t] = y / L;
    __syncthreads();
    float g = 0.f;
    #pragma unroll 8
    for (int v = 0; v < VOC; ++v) g += y2[v] * emb[t * VOC + v];
    out[(size_t)b * VOC + t] = co * g;
}

// ------------------------------------------------------------------
// plq[v] = pos[last] @ WQ2_bot.  Grid(1), 128 threads.
// ------------------------------------------------------------------
__global__ __launch_bounds__(128) void plq_k(
    const float* __restrict__ pos, const float* __restrict__ WQ2,
    float* __restrict__ plq)
{
    const int t = threadIdx.x;
    float acc = 0.f;
    for (int d = 0; d < SEQ; ++d)
        acc += pos[(size_t)(SEQ - 1) * SEQ + d] * WQ2[(size_t)(VOC + d) * VOC + t];
    plq[t] = acc;
}

// ------------------------------------------------------------------
extern "C" void kernel_launch(void* const* d_in, const int* in_sizes, int n_in,
                              void* d_out, int out_size, void* d_ws, size_t ws_size,
                              hipStream_t stream)
{
    const int* tok = (const int*)d_in[0];
    const float* emb = (const float*)d_in[1];
    const float* pos = (const float*)d_in[2];
    const float* WQ1 = (const float*)d_in[3];
    const float* WK1 = (const float*)d_in[4];
    const float* WV1 = (const float*)d_in[5];
    const float* WQ2 = (const float*)d_in[6];
    const float* WK2 = (const float*)d_in[7];
    const float* WV2 = (const float*)d_in[8];
    const float* beta1 = (const float*)d_in[9];
    const float* beta2 = (const float*)d_in[10];
    const float* beta_out = (const float*)d_in[11];
    float* out = (float*)d_out;

    if (ws_size < 178651136ull) return;

    char* wsb = (char*)d_ws;
    #define MB_(x) ((size_t)(x) * 1048576ull)
    // Split-buffer region: aliased with O (all splits dead before attn runs)
    unsigned short* posH = (unsigned short*)(wsb + MB_(0));
    unsigned short* posL = (unsigned short*)(wsb + MB_(8));
    unsigned short* WTH  = (unsigned short*)(wsb + MB_(16));
    unsigned short* WTL  = (unsigned short*)(wsb + MB_(25));
    unsigned short* QpH  = (unsigned short*)(wsb + MB_(34));
    unsigned short* QpL  = (unsigned short*)(wsb + MB_(42));
    unsigned short* KpH  = (unsigned short*)(wsb + MB_(50));
    unsigned short* KpL  = (unsigned short*)(wsb + MB_(58));
    unsigned short* VpH  = (unsigned short*)(wsb + MB_(66));
    unsigned short* VpL  = (unsigned short*)(wsb + MB_(75));
    unsigned short* TqH  = (unsigned short*)(wsb + MB_(84));
    unsigned short* TqL  = (unsigned short*)(wsb + MB_(84) + 524288);
    unsigned short* TkH  = (unsigned short*)(wsb + MB_(85));
    unsigned short* TkL  = (unsigned short*)(wsb + MB_(85) + 524288);
    float* O = (float*)(wsb + MB_(0));    // 128 MB, aliases the splits

    float* fp = (float*)(wsb + MB_(128));
    auto take = [&](size_t n) { float* p = fp; fp += n; return p; };
    float* Gqk = take((size_t)2048 * 2048);
    float* Gtk = take((size_t)128 * 2048);
    float* Gqt = take((size_t)2048 * 128);
    float* Gtt = take((size_t)128 * 128);
    float* Tq  = take((size_t)128 * 2048);
    float* Tk  = take((size_t)128 * 2048);
    float* Tv  = take((size_t)128 * 2176);
    float* TxK = take((size_t)128 * 128);
    float* TxV = take((size_t)128 * 128);
    float* TvK = take((size_t)128 * 128);
    float* TvV = take((size_t)128 * 128);
    float* TvQ = take((size_t)128 * 128);
    float* TxQ = take((size_t)128 * 128);
    float* VpKVQ = take((size_t)2048 * 384);   // [s][K2|V2|Q2] = Vp @ [WK2|WV2|WQ2]
    float* PxKV  = take((size_t)2048 * 256);   // [s][K2|V2] = pos @ [WK2b|WV2b]
    float* plq = take((size_t)128);
    float* a1g = take((size_t)NB * 2048);
    float* wg  = take((size_t)NB * 128);
    float* q2  = take((size_t)NB * 128);
    float* part = take((size_t)NB * 8 * 132);

    dim3 blk(256);

    // --- tiny token-table GEMMs (f32) ---
    hipLaunchKernelGGL((gemm_f32<0>), dim3(32, 2), blk, 0, stream, emb, 128, WQ1, 2048, Tq, 2048, 128, 2048, 128);
    hipLaunchKernelGGL((gemm_f32<0>), dim3(32, 2), blk, 0, stream, emb, 128, WK1, 2048, Tk, 2048, 128, 2048, 128);
    hipLaunchKernelGGL((gemm_f32<0>), dim3(34, 2), blk, 0, stream, emb, 128, WV1, 2176, Tv, 2176, 128, 2176, 128);
    hipLaunchKernelGGL((gemm_f32<0>), dim3(2, 2),  blk, 0, stream, emb, 128, WK2, 128, TxK, 128, 128, 128, 128);
    hipLaunchKernelGGL((gemm_f32<0>), dim3(2, 2),  blk, 0, stream, emb, 128, WV2, 128, TxV, 128, 128, 128, 128);
    hipLaunchKernelGGL((gemm_f32<0>), dim3(2, 2),  blk, 0, stream, emb, 128, WQ2, 128, TxQ, 128, 128, 128, 128);
    hipLaunchKernelGGL(plq_k, dim3(1), dim3(128), 0, stream, pos, WQ2, plq);

    // --- splits + big MFMA GEMMs ---
    hipLaunchKernelGGL(split_plain, dim3(4096), blk, 0, stream, pos, posH, posL, 1048576);
    hipLaunchKernelGGL(splitT, dim3(64, 64), blk, 0, stream, WQ1, 2048, 128, 2048, 2048, WTH, WTL);
    hipLaunchKernelGGL((gemm_nt_mfma<2>), dim3(16, 16), blk, 0, stream,
                       posH, posL, 2048, WTH, WTL, 2048, (float*)nullptr, QpH, QpL, 2048, 2048);
    hipLaunchKernelGGL(splitT, dim3(64, 64), blk, 0, stream, WK1, 2048, 128, 2048, 2048, WTH, WTL);
    hipLaunchKernelGGL((gemm_nt_mfma<2>), dim3(16, 16), blk, 0, stream,
                       posH, posL, 2048, WTH, WTL, 2048, (float*)nullptr, KpH, KpL, 2048, 2048);
    hipLaunchKernelGGL(splitT, dim3(64, 68), blk, 0, stream, WV1, 2176, 128, 2048, 2176, WTH, WTL);
    hipLaunchKernelGGL((gemm_nt_mfma<2>), dim3(17, 16), blk, 0, stream,
                       posH, posL, 2048, WTH, WTL, 2048, (float*)nullptr, VpH, VpL, 2176, 2048);
    hipLaunchKernelGGL((gemm_nt_mfma<1>), dim3(16, 16), blk, 0, stream,
                       QpH, QpL, 2048, KpH, KpL, 2048, Gqk, (unsigned short*)nullptr, (unsigned short*)nullptr, 2048, 2048);
    hipLaunchKernelGGL(split_plain, dim3(256), blk, 0, stream, Tq, TqH, TqL, 65536);
    hipLaunchKernelGGL(split_plain, dim3(256), blk, 0, stream, Tk, TkH, TkL, 65536);
    hipLaunchKernelGGL((gemm_nt_mfma<1>), dim3(16, 1), blk, 0, stream,
                       TqH, TqL, 2048, KpH, KpL, 2048, Gtk, (unsigned short*)nullptr, (unsigned short*)nullptr, 2048, 2048);
    hipLaunchKernelGGL((gemm_nt_mfma<1>), dim3(1, 16), blk, 0, stream,
                       QpH, QpL, 2048, TkH, TkL, 2048, Gqt, (unsigned short*)nullptr, (unsigned short*)nullptr, 128, 2048);
    hipLaunchKernelGGL((gemm_nt_mfma<1>), dim3(1, 1), blk, 0, stream,
                       TqH, TqL, 2048, TkH, TkL, 2048, Gtt, (unsigned short*)nullptr, (unsigned short*)nullptr, 128, 2048);
    // PxKV: pos @ [WK2_bot | WV2_bot]  (combined, A read once)
    hipLaunchKernelGGL(splitT, dim3(64, 4), blk, 0, stream, WK2, 128, 128, 2048, 128, WTH, WTL);
    hipLaunchKernelGGL(splitT, dim3(64, 4), blk, 0, stream, WV2, 128, 128, 2048, 128,
                       WTH + (size_t)128 * 2048, WTL + (size_t)128 * 2048);
    hipLaunchKernelGGL((gemm_nt_mfma<1>), dim3(2, 16), blk, 0, stream,
                       posH, posL, 2048, WTH, WTL, 2048, PxKV, (unsigned short*)nullptr, (unsigned short*)nullptr, 256, 2048);
    // VpKVQ: Vp @ [WK2 | WV2 | WQ2]  (combined, A read once)
    hipLaunchKernelGGL(splitT, dim3(68, 4), blk, 0, stream, WK2, 128, 0, 2176, 128, WTH, WTL);
    hipLaunchKernelGGL(splitT, dim3(68, 4), blk, 0, stream, WV2, 128, 0, 2176, 128,
                       WTH + (size_t)128 * 2176, WTL + (size_t)128 * 2176);
    hipLaunchKernelGGL(splitT, dim3(68, 4), blk, 0, stream, WQ2, 128, 0, 2176, 128,
                       WTH + (size_t)256 * 2176, WTL + (size_t)256 * 2176);
    hipLaunchKernelGGL((gemm_nt_mfma<1>), dim3(3, 16), blk, 0, stream,
                       VpH, VpL, 2176, WTH, WTL, 2176, VpKVQ, (unsigned short*)nullptr, (unsigned short*)nullptr, 384, 2176);
    hipLaunchKernelGGL((gemm_f32<0>), dim3(2, 2), blk, 0, stream, Tv, 2176, WK2, 128, TvK, 128, 128, 128, 2176);
    hipLaunchKernelGGL((gemm_f32<0>), dim3(2, 2), blk, 0, stream, Tv, 2176, WV2, 128, TvV, 128, 128, 128, 2176);
    hipLaunchKernelGGL((gemm_f32<0>), dim3(2, 2), blk, 0, stream, Tv, 2176, WQ2, 128, TvQ, 128, 128, 128, 2176);

    // --- attention core (writes O; splits region is dead by now) ---
    hipLaunchKernelGGL(attn_mfma, dim3(32, 64), blk, 0, stream,
                       tok, Gtt, Gtk, Gqt, Gqk, TvK, TvV, VpKVQ, beta1, O);

    // --- stage 2 (parallel decomposition) ---
    hipLaunchKernelGGL(s2_p1, dim3(NB), blk, 0, stream,
                       tok, Gtt, Gtk, Gqt, Gqk, beta1, a1g, wg);
    hipLaunchKernelGGL(s2_q2k, dim3(NB), blk, 0, stream,
                       tok, a1g, wg, VpKVQ, TvQ, TxQ, plq, q2);
    hipLaunchKernelGGL(s2_p3a, dim3(8, NB), blk, 0, stream,
                       tok, q2, TxK, PxKV, TxV, O, beta2, part);
    hipLaunchKernelGGL(s2_p3b, dim3(NB), dim3(128), 0, stream,
                       part, emb, beta_out, out);
}

// Round 7
// 1673.539 us; speedup vs baseline: 2.1821x; 1.4364x over previous
//
#include <hip/hip_runtime.h>
#include <cmath>

#define SEQ 2048
#define NB 64
#define VOC 128
#define DM 2176
#define NEG_INF -1e30f

typedef __attribute__((ext_vector_type(8))) short short8;
typedef __attribute__((ext_vector_type(4))) float f32x4;
typedef __attribute__((ext_vector_type(4))) unsigned int uint4v;
typedef __attribute__((ext_vector_type(2))) unsigned int uint2v;

// ---------- bf16 split helpers (hi = truncation, lo = remainder) ----------
__device__ __forceinline__ void splitf(float x, unsigned short& h, unsigned short& l) {
    unsigned int u = __float_as_uint(x);
    h = (unsigned short)(u >> 16);
    float d = x - __uint_as_float(u & 0xFFFF0000u);
    l = (unsigned short)(__float_as_uint(d) >> 16);
}
__device__ __forceinline__ unsigned int bfpair(float x0, float x1, unsigned int& lopair) {
    unsigned int u0 = __float_as_uint(x0), u1 = __float_as_uint(x1);
    float d0 = x0 - __uint_as_float(u0 & 0xFFFF0000u);
    float d1 = x1 - __uint_as_float(u1 & 0xFFFF0000u);
    lopair = (__float_as_uint(d0) >> 16) | (__float_as_uint(d1) & 0xFFFF0000u);
    return (u0 >> 16) | (u1 & 0xFFFF0000u);
}

// ------------------------------------------------------------------
// Naive tiled f32 GEMM (tiny GEMMs only). C[M,N] = A[M,K] @ B[K,N].
// ------------------------------------------------------------------
template<int TB>
__global__ __launch_bounds__(256) void gemm_f32(
    const float* __restrict__ A, int lda,
    const float* __restrict__ B, int ldb,
    float* __restrict__ C, int ldc,
    int M, int N, int K)
{
    __shared__ float As[16][64];
    __shared__ float Bs[16][65];
    const int bm = blockIdx.y * 64;
    const int bn = blockIdx.x * 64;
    const int t  = threadIdx.x;
    const int tx = t & 15, ty = t >> 4;
    float acc[4][4] = {};
    for (int k0 = 0; k0 < K; k0 += 16) {
        #pragma unroll
        for (int i = 0; i < 4; ++i) {
            int m = (t >> 4) + 16 * i;
            int k = t & 15;
            As[k][m] = A[(size_t)(bm + m) * lda + k0 + k];
        }
        if (TB == 0) {
            #pragma unroll
            for (int i = 0; i < 4; ++i) {
                int n = t & 63;
                int k = (t >> 6) + 4 * i;
                Bs[k][n] = B[(size_t)(k0 + k) * ldb + bn + n];
            }
        } else {
            #pragma unroll
            for (int i = 0; i < 4; ++i) {
                int k = t & 15;
                int n = (t >> 4) + 16 * i;
                Bs[k][n] = B[(size_t)(bn + n) * ldb + k0 + k];
            }
        }
        __syncthreads();
        #pragma unroll
        for (int kk = 0; kk < 16; ++kk) {
            float a[4], bb[4];
            #pragma unroll
            for (int i = 0; i < 4; ++i) a[i] = As[kk][ty * 4 + i];
            #pragma unroll
            for (int j = 0; j < 4; ++j) bb[j] = Bs[kk][tx * 4 + j];
            #pragma unroll
            for (int i = 0; i < 4; ++i)
                #pragma unroll
                for (int j = 0; j < 4; ++j)
                    acc[i][j] += a[i] * bb[j];
        }
        __syncthreads();
    }
    #pragma unroll
    for (int i = 0; i < 4; ++i) {
        size_t m = bm + ty * 4 + i;
        #pragma unroll
        for (int j = 0; j < 4; ++j)
            C[m * ldc + bn + tx * 4 + j] = acc[i][j];
    }
}

// ------------------------------------------------------------------
__global__ __launch_bounds__(256) void split_plain(
    const float* __restrict__ in, unsigned short* __restrict__ oh,
    unsigned short* __restrict__ ol, int n4)
{
    int i = blockIdx.x * 256 + threadIdx.x;
    if (i >= n4) return;
    f32x4 v = *(const f32x4*)(in + (size_t)i * 4);
    unsigned int h01, h23, l01, l23;
    h01 = bfpair(v[0], v[1], l01);
    h23 = bfpair(v[2], v[3], l23);
    *(uint2v*)(oh + (size_t)i * 4) = (uint2v){h01, h23};
    *(uint2v*)(ol + (size_t)i * 4) = (uint2v){l01, l23};
}

// ------------------------------------------------------------------
// Split + transpose: out[c][r] = in[(row0+r)*ld + c], r<NR, c<NC. out ld = NR.
// Grid (NR/32, NC/32), 256 threads.
// ------------------------------------------------------------------
__global__ __launch_bounds__(256) void splitT(
    const float* __restrict__ in, int ld, int row0,
    int NR, int NC,
    unsigned short* __restrict__ oh, unsigned short* __restrict__ ol)
{
    __shared__ float tile[32][33];
    const int r0 = blockIdx.x * 32, c0 = blockIdx.y * 32;
    const int t = threadIdx.x;
    const int x = t & 31, y = t >> 5;
    #pragma unroll
    for (int i = 0; i < 4; ++i) {
        int r = y + i * 8;
        tile[r][x] = in[(size_t)(row0 + r0 + r) * ld + c0 + x];
    }
    __syncthreads();
    #pragma unroll
    for (int i = 0; i < 4; ++i) {
        int c = y + i * 8;
        float v = tile[x][c];
        unsigned short h, l;
        splitf(v, h, l);
        size_t o = (size_t)(c0 + c) * NR + r0 + x;
        oh[o] = h; ol[o] = l;
    }
}

// ------------------------------------------------------------------
// Split-bf16 MFMA GEMM (NT): C[M,N] = (Ah+Al)[M,K] @ (Bh+Bl)[N,K]^T
// 3-term. Tile 128x128, BK=64, 4 waves. MODE bit0: f32 C; bit1: split Ch/Cl.
// ------------------------------------------------------------------
template<int MODE>
__global__ __launch_bounds__(256, 2) void gemm_nt_mfma(
    const unsigned short* __restrict__ Ah, const unsigned short* __restrict__ Al, int lda,
    const unsigned short* __restrict__ Bh, const unsigned short* __restrict__ Bl, int ldb,
    float* __restrict__ C, unsigned short* __restrict__ Ch, unsigned short* __restrict__ Cl,
    int ldc, int K)
{
    __shared__ __align__(16) unsigned short sAh[128 * 64], sAl[128 * 64];
    __shared__ __align__(16) unsigned short sBh[128 * 64], sBl[128 * 64];
    const int bm = blockIdx.y * 128, bn = blockIdx.x * 128;
    const int t = threadIdx.x;
    const int lane = t & 63, wave = t >> 6;
    const int wr = wave >> 1, wc = wave & 1;
    const int lr = lane & 15;

    f32x4 acc[4][4];
    #pragma unroll
    for (int i = 0; i < 4; ++i)
        #pragma unroll
        for (int j = 0; j < 4; ++j) acc[i][j] = (f32x4){0.f, 0.f, 0.f, 0.f};

    for (int k0 = 0; k0 < K; k0 += 64) {
        __syncthreads();
        #pragma unroll
        for (int i = 0; i < 4; ++i) {
            int idx = t + i * 256;
            int r = idx >> 3, kc = (idx & 7) * 8;
            int off = (r * 128 + kc * 2) ^ ((r & 7) << 4);
            size_t ga = (size_t)(bm + r) * lda + k0 + kc;
            size_t gb = (size_t)(bn + r) * ldb + k0 + kc;
            *(short8*)((char*)sAh + off) = *(const short8*)(Ah + ga);
            *(short8*)((char*)sAl + off) = *(const short8*)(Al + ga);
            *(short8*)((char*)sBh + off) = *(const short8*)(Bh + gb);
            *(short8*)((char*)sBl + off) = *(const short8*)(Bl + gb);
        }
        __syncthreads();
        #pragma unroll
        for (int ks = 0; ks < 2; ++ks) {
            const int kby = ks * 64 + ((lane >> 4) << 4);
            short8 ah[4], al[4];
            #pragma unroll
            for (int rf = 0; rf < 4; ++rf) {
                int row = wr * 64 + rf * 16 + lr;
                int off = (row * 128 + kby) ^ ((row & 7) << 4);
                ah[rf] = *(const short8*)((const char*)sAh + off);
                al[rf] = *(const short8*)((const char*)sAl + off);
            }
            #pragma unroll
            for (int cf = 0; cf < 4; ++cf) {
                int col = wc * 64 + cf * 16 + lr;
                int off = (col * 128 + kby) ^ ((col & 7) << 4);
                short8 bh = *(const short8*)((const char*)sBh + off);
                short8 bl = *(const short8*)((const char*)sBl + off);
                #pragma unroll
                for (int rf = 0; rf < 4; ++rf) {
                    acc[rf][cf] = __builtin_amdgcn_mfma_f32_16x16x32_bf16(ah[rf], bh, acc[rf][cf], 0, 0, 0);
                    acc[rf][cf] = __builtin_amdgcn_mfma_f32_16x16x32_bf16(ah[rf], bl, acc[rf][cf], 0, 0, 0);
                    acc[rf][cf] = __builtin_amdgcn_mfma_f32_16x16x32_bf16(al[rf], bh, acc[rf][cf], 0, 0, 0);
                }
            }
        }
    }
    #pragma unroll
    for (int rf = 0; rf < 4; ++rf) {
        #pragma unroll
        for (int j = 0; j < 4; ++j) {
            int row = bm + wr * 64 + rf * 16 + ((lane >> 4) << 2) + j;
            #pragma unroll
            for (int cf = 0; cf < 4; ++cf) {
                int col = bn + wc * 64 + cf * 16 + lr;
                float v = acc[rf][cf][j];
                size_t o = (size_t)row * ldc + col;
                if (MODE & 1) C[o] = v;
                if (MODE & 2) { unsigned short h, l; splitf(v, h, l); Ch[o] = h; Cl[o] = l; }
            }
        }
    }
}

// ------------------------------------------------------------------
// MFMA attention core (round-5 structure; unified G / VpKVQ tables).
// G[2176][2176]: G[q][k]=Gqk (q,k<2048); G[2048+t][k]=Gtk; G[q][2048+t]=Gqt;
//               G[2048+t][2048+t']=Gtt.
// VpKVQ[2176][384]: rows 0..2047 = Vp@[WK2|WV2|WQ2]; rows 2048.. = Tv@same.
// Grid (SEQ/64, NB), 256 threads.
// ------------------------------------------------------------------
__global__ __launch_bounds__(256, 2) void attn_mfma(
    const int* __restrict__ tok,
    const float* __restrict__ G,
    const float* __restrict__ VpKVQ,
    const float* __restrict__ beta1,
    float* __restrict__ O)
{
    const int b = blockIdx.y;
    const int q0 = blockIdx.x * 64;
    const int t = threadIdx.x;
    const int lane = t & 63, wave = t >> 6;
    const float c1 = beta1[0] * 1.12890625f;

    __shared__ __align__(16) unsigned short Mh[256 * 32], Ml[256 * 32];  // [c][k]
    __shared__ __align__(16) unsigned short Ph[64 * 32], Pl[64 * 32];    // [q][k]
    __shared__ float GT[64 * 128];
    __shared__ float m_s[64], l_s[64], rs_s[64];
    __shared__ int tq_s[64], tk_s[32];

    if (t < 64) {
        tq_s[t] = tok[(size_t)b * SEQ + q0 + t];
        m_s[t] = NEG_INF;
        l_s[t] = 0.f;
    }
    __syncthreads();
    // ---- GT[q][tk] = Gqt + Gtt (one coalesced pass) ----
    {
        const int c4 = (t & 31) * 4;
        #pragma unroll
        for (int i = 0; i < 8; ++i) {
            int q = (t >> 5) + i * 8;
            f32x4 a = *(const f32x4*)&G[(size_t)(q0 + q) * 2176 + 2048 + c4];
            f32x4 g = *(const f32x4*)&G[(size_t)(2048 + tq_s[q]) * 2176 + 2048 + c4];
            *(f32x4*)&GT[q * 128 + c4] = a + g;
        }
    }

    f32x4 acc[4][4];
    #pragma unroll
    for (int i = 0; i < 4; ++i)
        #pragma unroll
        for (int j = 0; j < 4; ++j) acc[i][j] = (f32x4){0.f, 0.f, 0.f, 0.f};

    const int qr = t >> 3;           // 0..31
    const int kb4 = (t & 7) * 4;     // 0..28
    const int lr = lane & 15;
    const int ksl = lane >> 4;       // 0..3
    const int cc = t & 127;
    const float* Tb = VpKVQ + (size_t)2048 * 384 + ((t < 128) ? 0 : 128);
    const float* Vb = VpKVQ + ((t < 128) ? 0 : 128);

    for (int k0 = 0; k0 < q0 + 64; k0 += 32) {
        if (t < 32) tk_s[t] = tok[(size_t)b * SEQ + k0 + t];
        __syncthreads();   // tk_s visible; prev MFMA done before M/P overwrite

        // ---- build M: thread owns column cc of its half; 4 granules ----
        #pragma unroll
        for (int g = 0; g < 4; ++g) {
            unsigned int hh[4], ll[4];
            #pragma unroll
            for (int p = 0; p < 4; ++p) {
                int kk = g * 8 + p * 2;
                float x0 = Tb[tk_s[kk] * 384 + cc]     + Vb[(size_t)(k0 + kk) * 384 + cc];
                float x1 = Tb[tk_s[kk + 1] * 384 + cc] + Vb[(size_t)(k0 + kk + 1) * 384 + cc];
                hh[p] = bfpair(x0, x1, ll[p]);
            }
            int i16 = t * 4 + ((g + (t >> 1)) & 3);
            *(uint4v*)((char*)Mh + i16 * 16) = (uint4v){hh[0], hh[1], hh[2], hh[3]};
            *(uint4v*)((char*)Ml + i16 * 16) = (uint4v){ll[0], ll[1], ll[2], ll[3]};
        }

        // ---- scores + wave-parallel online softmax (2 q-rows/thread) ----
        #pragma unroll
        for (int rr = 0; rr < 2; ++rr) {
            const int q = qr + rr * 32;
            const int qg = q0 + q;
            f32x4 gqk = *(const f32x4*)&G[(size_t)qg * 2176 + k0 + kb4];
            f32x4 gtk = *(const f32x4*)&G[(size_t)(2048 + tq_s[q]) * 2176 + k0 + kb4];
            float s[4];
            #pragma unroll
            for (int j = 0; j < 4; ++j) {
                int kg = k0 + kb4 + j;
                s[j] = (kg <= qg)
                     ? c1 * (gqk[j] + gtk[j] + GT[q * 128 + tk_s[kb4 + j]])
                     : NEG_INF;
            }
            float tmax = fmaxf(fmaxf(s[0], s[1]), fmaxf(s[2], s[3]));
            tmax = fmaxf(tmax, __shfl_xor(tmax, 1));
            tmax = fmaxf(tmax, __shfl_xor(tmax, 2));
            tmax = fmaxf(tmax, __shfl_xor(tmax, 4));
            const float m_old = m_s[q];
            const float mnew = fmaxf(m_old, tmax);
            float p0 = __expf(s[0] - mnew), p1 = __expf(s[1] - mnew);
            float p2 = __expf(s[2] - mnew), p3 = __expf(s[3] - mnew);
            float lsum = p0 + p1 + p2 + p3;
            lsum += __shfl_xor(lsum, 1);
            lsum += __shfl_xor(lsum, 2);
            lsum += __shfl_xor(lsum, 4);
            unsigned int l01, l23;
            unsigned int h01 = bfpair(p0, p1, l01);
            unsigned int h23 = bfpair(p2, p3, l23);
            int i16 = q * 4 + (((kb4 >> 3) + (q >> 1)) & 3);
            int pbyte = i16 * 16 + ((kb4 & 4) << 1);
            *(uint2v*)((char*)Ph + pbyte) = (uint2v){h01, h23};
            *(uint2v*)((char*)Pl + pbyte) = (uint2v){l01, l23};
            if ((t & 7) == 0) {
                float rs = __expf(m_old - mnew);
                m_s[q] = mnew;
                l_s[q] = l_s[q] * rs + lsum;
                rs_s[q] = rs;
            }
        }
        __syncthreads();

        // ---- rescale acc + MFMA P@M ----
        short8 pah[4], pal[4];
        f32x4 rsv[4];
        #pragma unroll
        for (int qf = 0; qf < 4; ++qf) {
            int row = qf * 16 + lr;
            int i16 = row * 4 + ((ksl + (row >> 1)) & 3);
            pah[qf] = *(const short8*)((const char*)Ph + i16 * 16);
            pal[qf] = *(const short8*)((const char*)Pl + i16 * 16);
            rsv[qf] = *(const f32x4*)&rs_s[qf * 16 + ksl * 4];
        }
        #pragma unroll
        for (int qf = 0; qf < 4; ++qf)
            #pragma unroll
            for (int cf = 0; cf < 4; ++cf)
                #pragma unroll
                for (int j = 0; j < 4; ++j)
                    acc[qf][cf][j] *= rsv[qf][j];
        #pragma unroll
        for (int cf = 0; cf < 4; ++cf) {
            int col = wave * 64 + cf * 16 + lr;
            int i16 = col * 4 + ((ksl + (col >> 1)) & 3);
            short8 bh = *(const short8*)((const char*)Mh + i16 * 16);
            short8 bl = *(const short8*)((const char*)Ml + i16 * 16);
            #pragma unroll
            for (int qf = 0; qf < 4; ++qf) {
                acc[qf][cf] = __builtin_amdgcn_mfma_f32_16x16x32_bf16(pah[qf], bh, acc[qf][cf], 0, 0, 0);
                acc[qf][cf] = __builtin_amdgcn_mfma_f32_16x16x32_bf16(pah[qf], bl, acc[qf][cf], 0, 0, 0);
                acc[qf][cf] = __builtin_amdgcn_mfma_f32_16x16x32_bf16(pal[qf], bh, acc[qf][cf], 0, 0, 0);
            }
        }
    }
    // ---- epilogue: divide by l, write O ----
    #pragma unroll
    for (int qf = 0; qf < 4; ++qf) {
        f32x4 lv = *(const f32x4*)&l_s[qf * 16 + ksl * 4];
        f32x4 inv;
        #pragma unroll
        for (int j = 0; j < 4; ++j) inv[j] = 1.0f / lv[j];
        #pragma unroll
        for (int j = 0; j < 4; ++j) {
            int row = q0 + qf * 16 + ksl * 4 + j;
            size_t base = ((size_t)b * SEQ + row) * 256 + wave * 64 + lr;
            #pragma unroll
            for (int cf = 0; cf < 4; ++cf)
                O[base + cf * 16] = acc[qf][cf][j] * inv[j];
        }
    }
}

// ------------------------------------------------------------------
// block reduce helpers
// ------------------------------------------------------------------
__device__ __forceinline__ float blk_reduce_max(float v, float* red, int t)
{
    red[t] = v; __syncthreads();
    #pragma unroll
    for (int s = 128; s >= 1; s >>= 1) {
        if (t < s) red[t] = fmaxf(red[t], red[t + s]);
        __syncthreads();
    }
    float r = red[0]; __syncthreads(); return r;
}
__device__ __forceinline__ float blk_reduce_sum(float v, float* red, int t)
{
    red[t] = v; __syncthreads();
    #pragma unroll
    for (int s = 128; s >= 1; s >>= 1) {
        if (t < s) red[t] += red[t + s];
        __syncthreads();
    }
    float r = red[0]; __syncthreads(); return r;
}

// ------------------------------------------------------------------
// Stage-2 P1: last-row attention weights + token bins. Grid (NB), 256 thr.
// ------------------------------------------------------------------
__global__ __launch_bounds__(256) void s2_p1(
    const int* __restrict__ tok,
    const float* __restrict__ G,
    const float* __restrict__ beta1,
    float* __restrict__ a1g, float* __restrict__ wg)
{
    const int b = blockIdx.x;
    const int t = threadIdx.x;
    const float c1 = beta1[0] * 1.12890625f;

    __shared__ float a_s[SEQ];
    __shared__ float red_s[256];
    __shared__ float w_s[VOC];

    const int* tokb = tok + (size_t)b * SEQ;
    const int tq = tokb[SEQ - 1];
    const float* Grow_q = G + (size_t)(SEQ - 1) * 2176;       // Gqk row + Gqt cols
    const float* Grow_t = G + (size_t)(2048 + tq) * 2176;     // Gtk row + Gtt cols

    float lmax = NEG_INF;
    for (int i = t; i < SEQ; i += 256) {
        int tk = tokb[i];
        float s = c1 * (Grow_t[2048 + tk] + Grow_t[i] + Grow_q[2048 + tk] + Grow_q[i]);
        a_s[i] = s;
        lmax = fmaxf(lmax, s);
    }
    float m = blk_reduce_max(lmax, red_s, t);
    float lsum = 0.f;
    for (int i = t; i < SEQ; i += 256) {
        float e = __expf(a_s[i] - m);
        a_s[i] = e;
        lsum += e;
    }
    float l = blk_reduce_sum(lsum, red_s, t);
    float inv = 1.f / l;
    if (t < VOC) w_s[t] = 0.f;
    __syncthreads();
    for (int i = t; i < SEQ; i += 256) {
        float a = a_s[i] * inv;
        a1g[(size_t)b * SEQ + i] = a;
        atomicAdd(&w_s[tokb[i]], a);
    }
    __syncthreads();
    if (t < VOC) wg[b * VOC + t] = w_s[t];
}

// ------------------------------------------------------------------
// Stage-2 P2: q2[b][v]. Grid (NB), 256 threads.
// ------------------------------------------------------------------
__global__ __launch_bounds__(256) void s2_q2k(
    const int* __restrict__ tok, const float* __restrict__ a1g,
    const float* __restrict__ wg, const float* __restrict__ VpKVQ,
    const float* __restrict__ Tx,
    const float* __restrict__ plq, float* __restrict__ q2)
{
    const int b = blockIdx.x, t = threadIdx.x;
    const int v = t & 127, half = t >> 7;
    __shared__ float red[256];
    const float* a1b = a1g + (size_t)b * SEQ;
    float acc = 0.f;
    for (int i = 0; i < 1024; ++i) {
        int s = half * 1024 + i;
        acc += a1b[s] * VpKVQ[(size_t)s * 384 + 256 + v];
    }
    if (half == 0) {
        const float* wb = wg + b * VOC;
        for (int tt = 0; tt < VOC; ++tt)
            acc += wb[tt] * VpKVQ[(size_t)(2048 + tt) * 384 + 256 + v];
    }
    red[t] = acc; __syncthreads();
    if (t < VOC) {
        int tq = tok[(size_t)b * SEQ + SEQ - 1];
        q2[b * VOC + t] = red[t] + red[t + 128] + Tx[tq * 384 + 256 + t] + plq[t];
    }
}

// ------------------------------------------------------------------
// Stage-2 P3a: split-flash over s. Grid (8, NB), 256 threads.
// Tx[128][384] = emb @ [WK2t|WV2t|WQ2t]; PxKV[2048][256].
// ------------------------------------------------------------------
__global__ __launch_bounds__(256) void s2_p3a(
    const int* __restrict__ tok, const float* __restrict__ q2,
    const float* __restrict__ Tx, const float* __restrict__ PxKV,
    const float* __restrict__ O, const float* __restrict__ beta2,
    float* __restrict__ part)
{
    const int b = blockIdx.y, c = blockIdx.x, t = threadIdx.x;
    const int s0 = c * 256;
    const float c2 = beta2[0] * 289.0f;

    __shared__ float q2s[VOC];
    __shared__ int   toks[256];
    __shared__ float es[256];
    __shared__ float red[256];

    if (t < VOC) q2s[t] = q2[b * VOC + t] * c2;
    toks[t] = tok[(size_t)b * SEQ + s0 + t];
    __syncthreads();

    const int s = s0 + t;
    const float* ok = O + ((size_t)b * SEQ + s) * 256;
    const float* xk = Tx + toks[t] * 384;
    const float* pk = PxKV + (size_t)s * 256;
    float dot = 0.f;
    #pragma unroll 8
    for (int v = 0; v < VOC; v += 4) {
        f32x4 a = *(const f32x4*)(ok + v);
        f32x4 x = *(const f32x4*)(xk + v);
        f32x4 p = *(const f32x4*)(pk + v);
        f32x4 q = *(const f32x4*)(q2s + v);
        dot += q[0] * (a[0] + x[0] + p[0]) + q[1] * (a[1] + x[1] + p[1])
             + q[2] * (a[2] + x[2] + p[2]) + q[3] * (a[3] + x[3] + p[3]);
    }
    float m = blk_reduce_max(dot, red, t);
    float e = __expf(dot - m);
    es[t] = e;
    float lsum = blk_reduce_sum(e, red, t);

    const int v = t & 127, half = t >> 7;
    float acc = 0.f;
    for (int i = 0; i < 128; ++i) {
        int si = half * 128 + i;
        float ee = es[si];
        acc += ee * (O[((size_t)b * SEQ + s0 + si) * 256 + 128 + v]
                   + Tx[toks[si] * 384 + 128 + v] + PxKV[(size_t)(s0 + si) * 256 + 128 + v]);
    }
    red[t] = acc; __syncthreads();
    float* pb = part + ((size_t)b * 8 + c) * 132;
    if (t < VOC) pb[t] = red[t] + red[t + 128];
    if (t == 128) { pb[128] = m; pb[129] = lsum; }
}

// ------------------------------------------------------------------
// Stage-2 P3b: combine 8 partials + logits. Grid (NB), 128 threads.
// ------------------------------------------------------------------
__global__ __launch_bounds__(128) void s2_p3b(
    const float* __restrict__ part, const float* __restrict__ emb,
    const float* __restrict__ beta_out, float* __restrict__ out)
{
    const int b = blockIdx.x, t = threadIdx.x;
    const float co = beta_out[0] * 70.09279563550022f;
    __shared__ float y2[VOC];
    const float* pb = part + (size_t)b * 8 * 132;
    float M = NEG_INF;
    #pragma unroll
    for (int c = 0; c < 8; ++c) M = fmaxf(M, pb[c * 132 + 128]);
    float L = 0.f, y = 0.f;
    #pragma unroll
    for (int c = 0; c < 8; ++c) {
        float sc = __expf(pb[c * 132 + 128] - M);
        L += pb[c * 132 + 129] * sc;
        y += pb[c * 132 + t] * sc;
    }
    y2[t] = y / L;
    __syncthreads();
    float g = 0.f;
    #pragma unroll 8
    for (int v = 0; v < VOC; ++v) g += y2[v] * emb[t * VOC + v];
    out[(size_t)b * VOC + t] = co * g;
}

// ------------------------------------------------------------------
// plq[v] = pos[last] @ WQ2_bot.  Grid(1), 128 threads.
// ------------------------------------------------------------------
__global__ __launch_bounds__(128) void plq_k(
    const float* __restrict__ pos, const float* __restrict__ WQ2,
    float* __restrict__ plq)
{
    const int t = threadIdx.x;
    float acc = 0.f;
    for (int d = 0; d < SEQ; ++d)
        acc += pos[(size_t)(SEQ - 1) * SEQ + d] * WQ2[(size_t)(VOC + d) * VOC + t];
    plq[t] = acc;
}

// ------------------------------------------------------------------
extern "C" void kernel_launch(void* const* d_in, const int* in_sizes, int n_in,
                              void* d_out, int out_size, void* d_ws, size_t ws_size,
                              hipStream_t stream)
{
    const int* tok = (const int*)d_in[0];
    const float* emb = (const float*)d_in[1];
    const float* pos = (const float*)d_in[2];
    const float* WQ1 = (const float*)d_in[3];
    const float* WK1 = (const float*)d_in[4];
    const float* WV1 = (const float*)d_in[5];
    const float* WQ2 = (const float*)d_in[6];
    const float* WK2 = (const float*)d_in[7];
    const float* WV2 = (const float*)d_in[8];
    const float* beta1 = (const float*)d_in[9];
    const float* beta2 = (const float*)d_in[10];
    const float* beta_out = (const float*)d_in[11];
    float* out = (float*)d_out;

    if (ws_size < 178651136ull) return;

    char* wsb = (char*)d_ws;
    #define MB_(x) ((size_t)(x) * 1048576ull)
    // --- O region (128 MB), aliased by all pre-attn split buffers ---
    float* O = (float*)(wsb + MB_(0));
    unsigned short* posH = (unsigned short*)(wsb + MB_(0));   // 8 MB
    unsigned short* posL = (unsigned short*)(wsb + MB_(8));   // 8 MB
    unsigned short* WTH  = (unsigned short*)(wsb + MB_(16));  // [6272][2048] 24.5 MB
    unsigned short* WTL  = (unsigned short*)(wsb + MB_(41));
    unsigned short* CH   = (unsigned short*)(wsb + MB_(66));  // [2176][6272] 26.1 MB
    unsigned short* CL   = (unsigned short*)(wsb + MB_(93));
    unsigned short* W2TH = (unsigned short*)(wsb + MB_(120)); // [384][2176] 1.6 MB
    unsigned short* W2TL = (unsigned short*)(wsb + MB_(122));

    // --- persistent region (after O) ---
    float* fp = (float*)(wsb + MB_(128));
    auto take = [&](size_t n) { float* p = fp; fp += n; return p; };
    float* G      = take((size_t)2176 * 2176);  // unified score tables
    float* VpKVQ  = take((size_t)2176 * 384);   // rows 0..2047 Vp@W2, 2048.. Tv@W2
    float* PxKV   = take((size_t)2048 * 256);
    float* Tx     = take((size_t)128 * 384);    // emb @ [WK2t|WV2t|WQ2t]
    float* T      = take((size_t)128 * 6272);   // emb @ [WQ1t|WK1t|WV1t] (f32, transient)
    float* plq    = take((size_t)128);
    float* a1g    = take((size_t)NB * 2048);
    float* wg     = take((size_t)NB * 128);
    float* q2     = take((size_t)NB * 128);
    float* part   = take((size_t)NB * 8 * 132);

    dim3 blk(256);
    const unsigned short* nuls = nullptr;
    float* nulf = nullptr;

    // --- token-row f32 GEMMs: T = emb @ [WQ1t|WK1t|WV1t] ---
    hipLaunchKernelGGL((gemm_f32<0>), dim3(32, 2), blk, 0, stream, emb, 128, WQ1, 2048, T, 6272, 128, 2048, 128);
    hipLaunchKernelGGL((gemm_f32<0>), dim3(32, 2), blk, 0, stream, emb, 128, WK1, 2048, T + 2048, 6272, 128, 2048, 128);
    hipLaunchKernelGGL((gemm_f32<0>), dim3(34, 2), blk, 0, stream, emb, 128, WV1, 2176, T + 4096, 6272, 128, 2176, 128);
    // --- Tx = emb @ [WK2t|WV2t|WQ2t] ---
    hipLaunchKernelGGL((gemm_f32<0>), dim3(2, 2), blk, 0, stream, emb, 128, WK2, 128, Tx, 384, 128, 128, 128);
    hipLaunchKernelGGL((gemm_f32<0>), dim3(2, 2), blk, 0, stream, emb, 128, WV2, 128, Tx + 128, 384, 128, 128, 128);
    hipLaunchKernelGGL((gemm_f32<0>), dim3(2, 2), blk, 0, stream, emb, 128, WQ2, 128, Tx + 256, 384, 128, 128, 128);
    hipLaunchKernelGGL(plq_k, dim3(1), dim3(128), 0, stream, pos, WQ2, plq);

    // --- splits ---
    hipLaunchKernelGGL(split_plain, dim3(4096), blk, 0, stream, pos, posH, posL, 1048576);
    hipLaunchKernelGGL(splitT, dim3(64, 64), blk, 0, stream, WQ1, 2048, 128, 2048, 2048, WTH, WTL);
    hipLaunchKernelGGL(splitT, dim3(64, 64), blk, 0, stream, WK1, 2048, 128, 2048, 2048,
                       WTH + (size_t)2048 * 2048, WTL + (size_t)2048 * 2048);
    hipLaunchKernelGGL(splitT, dim3(64, 68), blk, 0, stream, WV1, 2176, 128, 2048, 2176,
                       WTH + (size_t)4096 * 2048, WTL + (size_t)4096 * 2048);
    hipLaunchKernelGGL(splitT, dim3(68, 4), blk, 0, stream, WK2, 128, 0, 2176, 128, W2TH, W2TL);
    hipLaunchKernelGGL(splitT, dim3(68, 4), blk, 0, stream, WV2, 128, 0, 2176, 128,
                       W2TH + (size_t)128 * 2176, W2TL + (size_t)128 * 2176);
    hipLaunchKernelGGL(splitT, dim3(68, 4), blk, 0, stream, WQ2, 128, 0, 2176, 128,
                       W2TH + (size_t)256 * 2176, W2TL + (size_t)256 * 2176);
    hipLaunchKernelGGL(split_plain, dim3(784), blk, 0, stream, T,
                       CH + (size_t)2048 * 6272, CL + (size_t)2048 * 6272, 200704);

    // --- GEMM1: C rows 0..2047 = pos @ [W1 bottoms]  (split out) ---
    hipLaunchKernelGGL((gemm_nt_mfma<2>), dim3(49, 16), blk, 0, stream,
                       posH, posL, 2048, WTH, WTL, 2048, nulf, CH, CL, 6272, 2048);
    // --- GEMM2: all four score tables: G = [Qp;Tq] @ [Kp;Tk]^T ---
    hipLaunchKernelGGL((gemm_nt_mfma<1>), dim3(17, 17), blk, 0, stream,
                       CH, CL, 6272, CH + 2048, CL + 2048, 6272,
                       G, (unsigned short*)nuls, (unsigned short*)nuls, 2176, 2048);
    // --- GEMM3: VpKVQ (+TvKVQ rows) = [Vp;Tv] @ [WK2|WV2|WQ2]^T ---
    hipLaunchKernelGGL((gemm_nt_mfma<1>), dim3(3, 17), blk, 0, stream,
                       CH + 4096, CL + 4096, 6272, W2TH, W2TL, 2176,
                       VpKVQ, (unsigned short*)nuls, (unsigned short*)nuls, 384, 2176);
    // --- GEMM4: PxKV = pos @ [WK2b|WV2b]^T ---
    hipLaunchKernelGGL((gemm_nt_mfma<1>), dim3(2, 16), blk, 0, stream,
                       posH, posL, 2048, W2TH + 128, W2TL + 128, 2176,
                       PxKV, (unsigned short*)nuls, (unsigned short*)nuls, 256, 2048);

    // --- attention core (writes O; O-region splits all dead by now) ---
    hipLaunchKernelGGL(attn_mfma, dim3(32, 64), blk, 0, stream,
                       tok, G, VpKVQ, beta1, O);

    // --- stage 2 ---
    hipLaunchKernelGGL(s2_p1, dim3(NB), blk, 0, stream, tok, G, beta1, a1g, wg);
    hipLaunchKernelGGL(s2_q2k, dim3(NB), blk, 0, stream, tok, a1g, wg, VpKVQ, Tx, plq, q2);
    hipLaunchKernelGGL(s2_p3a, dim3(8, NB), blk, 0, stream, tok, q2, Tx, PxKV, O, beta2, part);
    hipLaunchKernelGGL(s2_p3b, dim3(NB), dim3(128), 0, stream, part, emb, beta_out, out);
}